// Round 13
// baseline (1282.675 us; speedup 1.0000x reference)
//
#include <hip/hip_runtime.h>

#define EMBD 50
#define HID 50
#define BLK 256
#define NT 13               // gate tiles: 13*16 = 208 rows >= 200 real gates
#define LOG2E 1.44269504f

typedef float f32x4 __attribute__((ext_vector_type(4)));
typedef short short8 __attribute__((ext_vector_type(8)));

__device__ __forceinline__ int imax(int a, int b) { return a > b ? a : b; }
__device__ __forceinline__ int imin(int a, int b) { return a < b ? a : b; }

__device__ __forceinline__ unsigned short f2bf(float f) {
    unsigned u = __float_as_uint(f);
    u += 0x7FFFu + ((u >> 16) & 1u);
    return (unsigned short)(u >> 16);
}
// Gate inputs arrive PRESCALED: sigmoid args by log2e, tanh args by 2*log2e.
__device__ __forceinline__ float s2f(float x) {       // sigmoid(g), x = g*log2e
    return __fdividef(1.0f, 1.0f + exp2f(-x));
}
__device__ __forceinline__ float t2f(float x) {       // tanh(g), x = g*2*log2e
    return 1.0f - __fdividef(2.0f, exp2f(x) + 1.0f);
}
__device__ __forceinline__ float tanhrt(float c) {    // tanh of runtime value
    return 1.0f - __fdividef(2.0f, exp2f((2.0f * LOG2E) * c) + 1.0f);
}
// (fallback only)
__device__ __forceinline__ float sigm(float x) {
    return __fdividef(1.0f, 1.0f + __expf(-x));
}
__device__ __forceinline__ float tanhfast(float x) {
    float e = __expf(2.0f * x);
    return 1.0f - __fdividef(2.0f, e + 1.0f);
}

// ---------------- length bucket sort ----------------
// ws ints: [0,25) counts, [25,50) bases, [50,75) cursors, [100,100+NW) perm
__global__ void zero_counts_kernel(int* ws) {
    if (threadIdx.x < 75) ws[threadIdx.x] = 0;
}
__global__ void hist_kernel(const int* __restrict__ lengths, int* ws, int nw) {
    int i = blockIdx.x * blockDim.x + threadIdx.x;
    if (i < nw) atomicAdd(&ws[lengths[i]], 1);
}
__global__ void prefix_kernel(int* ws) {
    if (threadIdx.x == 0 && blockIdx.x == 0) {
        int acc = 0;
        for (int l = 0; l <= 24; ++l) { ws[25 + l] = acc; acc += ws[l]; }
    }
}
__global__ void scatter_kernel(const int* __restrict__ lengths, int* ws, int nw) {
    int i = blockIdx.x * blockDim.x + threadIdx.x;
    if (i < nw) {
        int l = lengths[i];
        int pos = ws[25 + l] + atomicAdd(&ws[50 + l], 1);
        ws[100 + pos] = i;
    }
}

// ---------------- packing kernels ----------------
__global__ void pack_emb_kernel(const float* __restrict__ emb, unsigned short* __restrict__ embp,
                                int vocab) {
    int i = blockIdx.x * blockDim.x + threadIdx.x;
    if (i >= vocab * 64) return;
    int v = i >> 6, e = i & 63;
    float val = (e < EMBD) ? emb[v * EMBD + e] : (e == 63 ? 1.0f : 0.0f);
    embp[i] = f2bf(val);
}

// 13-tile weight pack (see R12 notes). Prescaled: i,f,o rows by log2e, g rows
// by 2*log2e.
__global__ void pack_w_kernel(const float* __restrict__ Wih_f, const float* __restrict__ Whh_f,
                              const float* __restrict__ b_f,
                              const float* __restrict__ Wih_b, const float* __restrict__ Whh_b,
                              const float* __restrict__ b_b,
                              unsigned short* __restrict__ wp) {
    int tid = blockIdx.x * blockDim.x + threadIdx.x;
    if (tid >= 2 * NT * 2048) return;          // 53248
    int i    = tid & 7;
    int lane = (tid >> 3) & 63;
    int kc   = (tid >> 9) & 3;
    int rem  = tid >> 11;
    int m    = rem % NT;
    int dir  = rem / NT;
    const float* Wih = dir ? Wih_b : Wih_f;
    const float* Whh = dir ? Whh_b : Whh_f;
    const float* bv  = dir ? b_b   : b_f;

    int p = lane & 15, grp = lane >> 4;
    int k = kc * 32 + 8 * grp + i;
    int s = p >> 2, q = p & 3;
    int cnt_s = (s < 2) ? 13 : 12;
    float val = 0.0f;
    if (m < cnt_s) {
        int j = 13 * s - (s == 3 ? 1 : 0) + m;
        int row = q * HID + j;
        if (k < 64) {
            if (k < EMBD)      val = Wih[row * EMBD + k];
            else if (k == 63)  val = bv[row];
        } else {
            int kk = k - 64;
            int half = kk >> 5;
            int s2 = (kk >> 3) & 3;
            int r = kk & 7;
            int mcol = half * 8 + r;
            int cnt2 = (s2 < 2) ? 13 : 12;
            if (mcol < cnt2) {
                int jc = 13 * s2 - (s2 == 3 ? 1 : 0) + mcol;
                val = Whh[row * HID + jc];
            }
        }
        val *= (q == 2) ? (2.0f * LOG2E) : LOG2E;
    }
    wp[tid] = f2bf(val);
}

// ---------------- main MFMA kernel ----------------
__device__ __forceinline__ f32x4 mf(const unsigned short* sWl, int m, int kc,
                                    short8 bb, f32x4 acc) {
    const short8 aw = *(const short8*)(sWl + (m * 4 + kc) * 512);
    return __builtin_amdgcn_mfma_f32_16x16x32_bf16(aw, bb, acc, 0, 0, 0);
}

// One j-element per lane per tile. Two INDEPENDENT 2-deep MFMA chains (x-part
// and h-part) summed at the end: halves matrix-pipe dependency depth.
#define TTM(M, C, H) {                                      \
    f32x4 ax = zz, ah = zz;                                 \
    ax = mf(sWl, (M), 0, cx0, ax);                          \
    ah = mf(sWl, (M), 2, bh0, ah);                          \
    ax = mf(sWl, (M), 1, cx1, ax);                          \
    ah = mf(sWl, (M), 3, bh1, ah);                          \
    f32x4 ac = ax + ah;                                     \
    float cn = s2f(ac[1]) * (C) + s2f(ac[0]) * t2f(ac[2]);  \
    float hn = s2f(ac[3]) * tanhrt(cn);                     \
    (C) = upd ? cn : (C);                                   \
    (H) = upd ? hn : (H); }

__global__ __launch_bounds__(BLK, 3)
void bilstm_mfma_kernel(const int* __restrict__ chars,
                        const int* __restrict__ lengths,
                        const int* __restrict__ perm,
                        const unsigned short* __restrict__ embp,
                        const unsigned short* __restrict__ wp,
                        float* __restrict__ out, int nw, int ml)
{
    const int dir = blockIdx.y;
    __shared__ unsigned short sW[NT * 4 * 512];   // 52 KB of A-fragments
    {
        const float4* src = (const float4*)(wp + dir * (NT * 4 * 512));
        float4* dst = (float4*)sW;
        for (int i = threadIdx.x; i < NT * 4 * 512 / 8; i += BLK) dst[i] = src[i];
    }
    __syncthreads();

    const int lane = threadIdx.x & 63;
    const int wv   = threadIdx.x >> 6;
    const int wcol = lane & 15;          // word column
    const int s    = lane >> 4;          // lane group

    int gidx = (blockIdx.x * 4 + wv) * 16 + wcol;
    gidx = imin(gidx, nw - 1);
    const int word = perm[gidx];
    const int len  = lengths[word];

    int lmax = len;
    lmax = imax(lmax, __shfl_xor(lmax, 1));
    lmax = imax(lmax, __shfl_xor(lmax, 2));
    lmax = imax(lmax, __shfl_xor(lmax, 4));
    lmax = imax(lmax, __shfl_xor(lmax, 8));

    const int* charp = chars + (size_t)word * ml;
    const unsigned short* sWl = sW + lane * 8;

    const f32x4 zz = {0.0f, 0.0f, 0.0f, 0.0f};
    float c00=0,c01=0,c02=0,c03=0,c04=0,c05=0,c06=0,c07=0,c08=0,c09=0,c10=0,c11=0,c12=0;
    float h00=0,h01=0,h02=0,h03=0,h04=0,h05=0,h06=0,h07=0,h08=0,h09=0,h10=0,h11=0,h12=0;
    short8 bh0, bh1;
#pragma unroll
    for (int i2 = 0; i2 < 8; ++i2) { bh0[i2] = 0; bh1[i2] = 0; }

    // prefetch x for t=0
    short8 cx0, cx1;
    if (lmax > 0) {
        int pos0 = dir ? imax(len - 1, 0) : 0;
        int ch = charp[pos0];
        cx0 = *(const short8*)(embp + ch * 64 + 8 * s);
        cx1 = *(const short8*)(embp + ch * 64 + 32 + 8 * s);
    }

    for (int t = 0; t < lmax; ++t) {
        // prefetch next step's x (latency hides under the MFMA blocks)
        int tn = (t + 1 < lmax) ? t + 1 : t;
        int posn = dir ? imax(len - 1 - tn, 0) : tn;
        int chn = charp[posn];
        short8 nx0 = *(const short8*)(embp + chn * 64 + 8 * s);
        short8 nx1 = *(const short8*)(embp + chn * 64 + 32 + 8 * s);

        const bool upd = (t < len);
        // bh0/bh1 hold PREVIOUS h throughout; rebuilt after all tiles.
        TTM(0,  c00, h00)
        TTM(1,  c01, h01)
        TTM(2,  c02, h02)
        TTM(3,  c03, h03)
        TTM(4,  c04, h04)
        TTM(5,  c05, h05)
        TTM(6,  c06, h06)
        TTM(7,  c07, h07)
        TTM(8,  c08, h08)
        TTM(9,  c09, h09)
        TTM(10, c10, h10)
        TTM(11, c11, h11)
        TTM(12, c12, h12)

        // repack h -> bf16 B-fragments (lane-local; bh1[5..7] stay 0: those
        // k-slots have all-zero weight columns)
        bh0[0] = (short)f2bf(h00); bh0[1] = (short)f2bf(h01);
        bh0[2] = (short)f2bf(h02); bh0[3] = (short)f2bf(h03);
        bh0[4] = (short)f2bf(h04); bh0[5] = (short)f2bf(h05);
        bh0[6] = (short)f2bf(h06); bh0[7] = (short)f2bf(h07);
        bh1[0] = (short)f2bf(h08); bh1[1] = (short)f2bf(h09);
        bh1[2] = (short)f2bf(h10); bh1[3] = (short)f2bf(h11);
        bh1[4] = (short)f2bf(h12);

        cx0 = nx0; cx1 = nx1;
    }

    // lane's j range: [off(s), off(s)+cnt(s)), contiguous
    int offs = 13 * s - (s == 3 ? 1 : 0);
    float* outw = out + (size_t)word * (2 * HID) + dir * HID + offs;
    outw[0] = h00; outw[1] = h01; outw[2]  = h02; outw[3]  = h03;
    outw[4] = h04; outw[5] = h05; outw[6]  = h06; outw[7]  = h07;
    outw[8] = h08; outw[9] = h09; outw[10] = h10; outw[11] = h11;
    if (s < 2) outw[12] = h12;   // pad element for s>=2
}

// ---------------- R1 fallback (scalar f32) ----------------
__global__ __launch_bounds__(BLK, 2)
void bilstm_fallback_kernel(const int* __restrict__ chars,
                            const int* __restrict__ lengths,
                            const float* __restrict__ emb,
                            const float* __restrict__ Wih_f, const float* __restrict__ Whh_f, const float* __restrict__ b_f,
                            const float* __restrict__ Wih_b, const float* __restrict__ Whh_b, const float* __restrict__ b_b,
                            const int* __restrict__ perm,
                            float* __restrict__ out, int nw, int ml)
{
    const int dir = blockIdx.y;
    const float* Wih = dir ? Wih_b : Wih_f;
    const float* Whh = dir ? Whh_b : Whh_f;
    const float* bv  = dir ? b_b  : b_f;
    __shared__ float4 sWU4[HID * 100];
    __shared__ float4 sB4[HID];
    {
        float* p = (float*)sWU4;
        for (int i = threadIdx.x; i < HID * 100 * 4; i += BLK) {
            int g = i & 3, r = i >> 2, j = r / 100, k = r - j * 100;
            p[i] = (k < EMBD) ? Wih[(j + g * HID) * EMBD + k]
                              : Whh[(j + g * HID) * HID + (k - EMBD)];
        }
        if (threadIdx.x < HID) {
            int j = threadIdx.x;
            sB4[j] = make_float4(bv[j], bv[j + HID], bv[j + 2*HID], bv[j + 3*HID]);
        }
    }
    __syncthreads();
    int gid = blockIdx.x * BLK + threadIdx.x;
    if (gid >= nw) return;
    int word = perm ? perm[gid] : gid;
    int len  = lengths[word];
    float h[HID], x[EMBD], c[HID], hn[HID];
#pragma unroll
    for (int j = 0; j < HID; ++j) h[j] = 0.f;
#pragma unroll 1
    for (int j = 0; j < HID; ++j) c[j] = 0.f;
    const int* wch = chars + word * ml;
    float* op = out + (size_t)word * (2 * HID) + dir * HID;
#pragma unroll 1
    for (int t = 0; t < len; ++t) {
        int pos = dir ? (len - 1 - t) : t;
        int ch = wch[pos];
        const float2* ep = (const float2*)(emb + ch * EMBD);
#pragma unroll
        for (int k = 0; k < EMBD / 2; ++k) { float2 v = ep[k]; x[2*k] = v.x; x[2*k+1] = v.y; }
#pragma unroll 1
        for (int j = 0; j < HID; ++j) {
            const float4* wpt = sWU4 + j * 100;
            float4 bb = sB4[j];
            float gi = bb.x, gf = bb.y, gg = bb.z, go = bb.w;
#pragma unroll
            for (int k = 0; k < EMBD; ++k) {
                float4 w = wpt[k]; float xv = x[k];
                gi += w.x*xv; gf += w.y*xv; gg += w.z*xv; go += w.w*xv;
            }
#pragma unroll
            for (int k = 0; k < HID; ++k) {
                float4 w = wpt[EMBD + k]; float hv = h[k];
                gi += w.x*hv; gf += w.y*hv; gg += w.z*hv; go += w.w*hv;
            }
            float cn = sigm(gf) * c[j] + sigm(gi) * tanhfast(gg);
            c[j] = cn;
            hn[j] = sigm(go) * tanhfast(cn);
        }
#pragma unroll
        for (int j = 0; j < HID; ++j) h[j] = hn[j];
    }
#pragma unroll
    for (int j = 0; j < HID / 2; ++j)
        ((float2*)op)[j] = make_float2(h[2*j], h[2*j+1]);
}

extern "C" void kernel_launch(void* const* d_in, const int* in_sizes, int n_in,
                              void* d_out, int out_size, void* d_ws, size_t ws_size,
                              hipStream_t stream) {
    const int*   chars = (const int*)  d_in[0];
    const int*   lens  = (const int*)  d_in[1];
    const float* emb   = (const float*)d_in[2];
    const float* Wih_f = (const float*)d_in[3];
    const float* Whh_f = (const float*)d_in[4];
    const float* b_f   = (const float*)d_in[5];
    const float* Wih_b = (const float*)d_in[6];
    const float* Whh_b = (const float*)d_in[7];
    const float* b_b   = (const float*)d_in[8];
    float* out = (float*)d_out;

    const int nw    = in_sizes[1];
    const int ml    = in_sizes[0] / nw;
    const int vocab = in_sizes[2] / EMBD;

    size_t sortNeed = (size_t)(100 + nw) * 4;
    size_t embOff   = (sortNeed + 255) & ~(size_t)255;
    size_t embBytes = (size_t)vocab * 64 * 2;
    size_t wOff     = (embOff + embBytes + 1023) & ~(size_t)1023;
    size_t need     = wOff + (size_t)2 * NT * 2048 * 2;   // 106496 B

    int* ws = (int*)d_ws;
    bool haveSort = ws_size >= sortNeed;
    if (haveSort) {
        zero_counts_kernel<<<1, 128, 0, stream>>>(ws);
        hist_kernel<<<(nw + 255) / 256, 256, 0, stream>>>(lens, ws, nw);
        prefix_kernel<<<1, 1, 0, stream>>>(ws);
        scatter_kernel<<<(nw + 255) / 256, 256, 0, stream>>>(lens, ws, nw);
    }

    if (ws_size >= need && haveSort) {
        unsigned short* embp = (unsigned short*)((char*)d_ws + embOff);
        unsigned short* wpk  = (unsigned short*)((char*)d_ws + wOff);
        pack_emb_kernel<<<(vocab * 64 + 255) / 256, 256, 0, stream>>>(emb, embp, vocab);
        pack_w_kernel<<<(2 * NT * 2048 + 255) / 256, 256, 0, stream>>>(
            Wih_f, Whh_f, b_f, Wih_b, Whh_b, b_b, wpk);
        dim3 grid((nw + 63) / 64, 2);
        bilstm_mfma_kernel<<<grid, BLK, 0, stream>>>(chars, lens, ws + 100, embp, wpk,
                                                     out, nw, ml);
    } else {
        dim3 grid((nw + BLK - 1) / BLK, 2);
        bilstm_fallback_kernel<<<grid, BLK, 0, stream>>>(chars, lens, emb,
                                                         Wih_f, Whh_f, b_f,
                                                         Wih_b, Whh_b, b_b,
                                                         haveSort ? ws + 100 : nullptr,
                                                         out, nw, ml);
    }
}

// Round 14
// 763.744 us; speedup vs baseline: 1.6795x; 1.6795x over previous
//
#include <hip/hip_runtime.h>

#define EMBD 50
#define HID 50
#define BLK 256
#define NT 13               // gate tiles: 13*16 = 208 rows >= 200 real gates
#define LOG2E 1.44269504f

typedef float f32x4 __attribute__((ext_vector_type(4)));
typedef short short8 __attribute__((ext_vector_type(8)));
typedef unsigned u32x4 __attribute__((ext_vector_type(4)));

__device__ __forceinline__ int imax(int a, int b) { return a > b ? a : b; }
__device__ __forceinline__ int imin(int a, int b) { return a < b ? a : b; }

__device__ __forceinline__ unsigned short f2bf(float f) {
    unsigned u = __float_as_uint(f);
    u += 0x7FFFu + ((u >> 16) & 1u);
    return (unsigned short)(u >> 16);
}

// Native-instruction transcendentals. Gate inputs arrive PRESCALED:
// sigmoid args by log2e, tanh args by 2*log2e.
__device__ __forceinline__ float s2f(float x) {       // sigmoid(g), x = g*log2e
    return __builtin_amdgcn_rcpf(1.0f + __builtin_amdgcn_exp2f(-x));
}
__device__ __forceinline__ float t2f(float x) {       // tanh(g), x = g*2*log2e
    return 1.0f - 2.0f * __builtin_amdgcn_rcpf(__builtin_amdgcn_exp2f(x) + 1.0f);
}
__device__ __forceinline__ float tanhrt(float c) {    // tanh of runtime value
    return 1.0f - 2.0f * __builtin_amdgcn_rcpf(
        __builtin_amdgcn_exp2f((2.0f * LOG2E) * c) + 1.0f);
}
// pack two f32 -> u32 of 2 bf16 (lo = a, hi = b), single instruction
__device__ __forceinline__ unsigned cvtpk(float a, float b) {
    unsigned r;
    asm("v_cvt_pk_bf16_f32 %0, %1, %2" : "=v"(r) : "v"(a), "v"(b));
    return r;
}
// (fallback only)
__device__ __forceinline__ float sigm(float x) {
    return __fdividef(1.0f, 1.0f + __expf(-x));
}
__device__ __forceinline__ float tanhfast(float x) {
    float e = __expf(2.0f * x);
    return 1.0f - __fdividef(2.0f, e + 1.0f);
}

// ---------------- length bucket sort ----------------
// ws ints: [0,25) counts, [25,50) bases, [50,75) cursors, [100,100+NW) perm
__global__ void zero_counts_kernel(int* ws) {
    if (threadIdx.x < 75) ws[threadIdx.x] = 0;
}
__global__ void hist_kernel(const int* __restrict__ lengths, int* ws, int nw) {
    int i = blockIdx.x * blockDim.x + threadIdx.x;
    if (i < nw) atomicAdd(&ws[lengths[i]], 1);
}
__global__ void prefix_kernel(int* ws) {
    if (threadIdx.x == 0 && blockIdx.x == 0) {
        int acc = 0;
        for (int l = 0; l <= 24; ++l) { ws[25 + l] = acc; acc += ws[l]; }
    }
}
__global__ void scatter_kernel(const int* __restrict__ lengths, int* ws, int nw) {
    int i = blockIdx.x * blockDim.x + threadIdx.x;
    if (i < nw) {
        int l = lengths[i];
        int pos = ws[25 + l] + atomicAdd(&ws[50 + l], 1);
        ws[100 + pos] = i;
    }
}

// ---------------- packing kernels ----------------
__global__ void pack_emb_kernel(const float* __restrict__ emb, unsigned short* __restrict__ embp,
                                int vocab) {
    int i = blockIdx.x * blockDim.x + threadIdx.x;
    if (i >= vocab * 64) return;
    int v = i >> 6, e = i & 63;
    float val = (e < EMBD) ? emb[v * EMBD + e] : (e == 63 ? 1.0f : 0.0f);
    embp[i] = f2bf(val);
}

// 13-tile weight pack (see R12 notes). Prescaled: i,f,o rows by log2e, g rows
// by 2*log2e.
__global__ void pack_w_kernel(const float* __restrict__ Wih_f, const float* __restrict__ Whh_f,
                              const float* __restrict__ b_f,
                              const float* __restrict__ Wih_b, const float* __restrict__ Whh_b,
                              const float* __restrict__ b_b,
                              unsigned short* __restrict__ wp) {
    int tid = blockIdx.x * blockDim.x + threadIdx.x;
    if (tid >= 2 * NT * 2048) return;          // 53248
    int i    = tid & 7;
    int lane = (tid >> 3) & 63;
    int kc   = (tid >> 9) & 3;
    int rem  = tid >> 11;
    int m    = rem % NT;
    int dir  = rem / NT;
    const float* Wih = dir ? Wih_b : Wih_f;
    const float* Whh = dir ? Whh_b : Whh_f;
    const float* bv  = dir ? b_b   : b_f;

    int p = lane & 15, grp = lane >> 4;
    int k = kc * 32 + 8 * grp + i;
    int s = p >> 2, q = p & 3;
    int cnt_s = (s < 2) ? 13 : 12;
    float val = 0.0f;
    if (m < cnt_s) {
        int j = 13 * s - (s == 3 ? 1 : 0) + m;
        int row = q * HID + j;
        if (k < 64) {
            if (k < EMBD)      val = Wih[row * EMBD + k];
            else if (k == 63)  val = bv[row];
        } else {
            int kk = k - 64;
            int half = kk >> 5;
            int s2 = (kk >> 3) & 3;
            int r = kk & 7;
            int mcol = half * 8 + r;
            int cnt2 = (s2 < 2) ? 13 : 12;
            if (mcol < cnt2) {
                int jc = 13 * s2 - (s2 == 3 ? 1 : 0) + mcol;
                val = Whh[row * HID + jc];
            }
        }
        val *= (q == 2) ? (2.0f * LOG2E) : LOG2E;
    }
    wp[tid] = f2bf(val);
}

// ---------------- main MFMA kernel ----------------
__device__ __forceinline__ f32x4 mf(const unsigned short* sWl, int m, int kc,
                                    short8 bb, f32x4 acc) {
    const short8 aw = *(const short8*)(sWl + (m * 4 + kc) * 512);
    return __builtin_amdgcn_mfma_f32_16x16x32_bf16(aw, bb, acc, 0, 0, 0);
}

// One j-element per lane per tile. Two independent 2-deep MFMA chains (x-part
// and h-part) summed at the end.
#define TTM(M, C, H) {                                      \
    f32x4 ax = zz, ah = zz;                                 \
    ax = mf(sWl, (M), 0, cx0, ax);                          \
    ah = mf(sWl, (M), 2, bh0, ah);                          \
    ax = mf(sWl, (M), 1, cx1, ax);                          \
    ah = mf(sWl, (M), 3, bh1, ah);                          \
    f32x4 ac = ax + ah;                                     \
    float cn = s2f(ac[1]) * (C) + s2f(ac[0]) * t2f(ac[2]);  \
    float hn = s2f(ac[3]) * tanhrt(cn);                     \
    (C) = upd ? cn : (C);                                   \
    (H) = upd ? hn : (H); }

__global__ __launch_bounds__(BLK, 2)
void bilstm_mfma_kernel(const int* __restrict__ chars,
                        const int* __restrict__ lengths,
                        const int* __restrict__ perm,
                        const unsigned short* __restrict__ embp,
                        const unsigned short* __restrict__ wp,
                        float* __restrict__ out, int nw, int ml)
{
    const int dir = blockIdx.y;
    __shared__ unsigned short sW[NT * 4 * 512];   // 52 KB of A-fragments
    {
        const float4* src = (const float4*)(wp + dir * (NT * 4 * 512));
        float4* dst = (float4*)sW;
        for (int i = threadIdx.x; i < NT * 4 * 512 / 8; i += BLK) dst[i] = src[i];
    }
    __syncthreads();

    const int lane = threadIdx.x & 63;
    const int wv   = threadIdx.x >> 6;
    const int wcol = lane & 15;          // word column
    const int s    = lane >> 4;          // lane group

    int gidx = (blockIdx.x * 4 + wv) * 16 + wcol;
    gidx = imin(gidx, nw - 1);
    const int word = perm[gidx];
    const int len  = lengths[word];

    int lmax = len;
    lmax = imax(lmax, __shfl_xor(lmax, 1));
    lmax = imax(lmax, __shfl_xor(lmax, 2));
    lmax = imax(lmax, __shfl_xor(lmax, 4));
    lmax = imax(lmax, __shfl_xor(lmax, 8));

    const int* charp = chars + (size_t)word * ml;
    const unsigned short* sWl = sW + lane * 8;

    const f32x4 zz = {0.0f, 0.0f, 0.0f, 0.0f};
    float c00=0,c01=0,c02=0,c03=0,c04=0,c05=0,c06=0,c07=0,c08=0,c09=0,c10=0,c11=0,c12=0;
    float h00=0,h01=0,h02=0,h03=0,h04=0,h05=0,h06=0,h07=0,h08=0,h09=0,h10=0,h11=0,h12=0;
    short8 bh0, bh1;
#pragma unroll
    for (int i2 = 0; i2 < 8; ++i2) { bh0[i2] = 0; bh1[i2] = 0; }

    // prefetch x for t=0
    short8 cx0, cx1;
    if (lmax > 0) {
        int pos0 = dir ? imax(len - 1, 0) : 0;
        int ch = charp[pos0];
        cx0 = *(const short8*)(embp + ch * 64 + 8 * s);
        cx1 = *(const short8*)(embp + ch * 64 + 32 + 8 * s);
    }

    for (int t = 0; t < lmax; ++t) {
        // prefetch next step's x (latency hides under the MFMA blocks)
        int tn = (t + 1 < lmax) ? t + 1 : t;
        int posn = dir ? imax(len - 1 - tn, 0) : tn;
        int chn = charp[posn];
        short8 nx0 = *(const short8*)(embp + chn * 64 + 8 * s);
        short8 nx1 = *(const short8*)(embp + chn * 64 + 32 + 8 * s);

        const bool upd = (t < len);
        // bh0/bh1 hold PREVIOUS h throughout; rebuilt after all tiles.
        TTM(0,  c00, h00)
        TTM(1,  c01, h01)
        TTM(2,  c02, h02)
        TTM(3,  c03, h03)
        TTM(4,  c04, h04)
        TTM(5,  c05, h05)
        TTM(6,  c06, h06)
        TTM(7,  c07, h07)
        TTM(8,  c08, h08)
        TTM(9,  c09, h09)
        TTM(10, c10, h10)
        TTM(11, c11, h11)
        TTM(12, c12, h12)

        // repack h -> bf16 B-fragments via v_cvt_pk_bf16_f32 (7 instrs).
        // bh1[5..7] stay 0: those k-slots have all-zero weight columns.
        u32x4 p0, p1;
        p0[0] = cvtpk(h00, h01); p0[1] = cvtpk(h02, h03);
        p0[2] = cvtpk(h04, h05); p0[3] = cvtpk(h06, h07);
        p1[0] = cvtpk(h08, h09); p1[1] = cvtpk(h10, h11);
        p1[2] = cvtpk(h12, 0.0f); p1[3] = 0u;
        bh0 = __builtin_bit_cast(short8, p0);
        bh1 = __builtin_bit_cast(short8, p1);

        cx0 = nx0; cx1 = nx1;
    }

    // lane's j range: [off(s), off(s)+cnt(s)), contiguous
    int offs = 13 * s - (s == 3 ? 1 : 0);
    float* outw = out + (size_t)word * (2 * HID) + dir * HID + offs;
    outw[0] = h00; outw[1] = h01; outw[2]  = h02; outw[3]  = h03;
    outw[4] = h04; outw[5] = h05; outw[6]  = h06; outw[7]  = h07;
    outw[8] = h08; outw[9] = h09; outw[10] = h10; outw[11] = h11;
    if (s < 2) outw[12] = h12;   // pad element for s>=2
}

// ---------------- R1 fallback (scalar f32) ----------------
__global__ __launch_bounds__(BLK, 2)
void bilstm_fallback_kernel(const int* __restrict__ chars,
                            const int* __restrict__ lengths,
                            const float* __restrict__ emb,
                            const float* __restrict__ Wih_f, const float* __restrict__ Whh_f, const float* __restrict__ b_f,
                            const float* __restrict__ Wih_b, const float* __restrict__ Whh_b, const float* __restrict__ b_b,
                            const int* __restrict__ perm,
                            float* __restrict__ out, int nw, int ml)
{
    const int dir = blockIdx.y;
    const float* Wih = dir ? Wih_b : Wih_f;
    const float* Whh = dir ? Whh_b : Whh_f;
    const float* bv  = dir ? b_b  : b_f;
    __shared__ float4 sWU4[HID * 100];
    __shared__ float4 sB4[HID];
    {
        float* p = (float*)sWU4;
        for (int i = threadIdx.x; i < HID * 100 * 4; i += BLK) {
            int g = i & 3, r = i >> 2, j = r / 100, k = r - j * 100;
            p[i] = (k < EMBD) ? Wih[(j + g * HID) * EMBD + k]
                              : Whh[(j + g * HID) * HID + (k - EMBD)];
        }
        if (threadIdx.x < HID) {
            int j = threadIdx.x;
            sB4[j] = make_float4(bv[j], bv[j + HID], bv[j + 2*HID], bv[j + 3*HID]);
        }
    }
    __syncthreads();
    int gid = blockIdx.x * BLK + threadIdx.x;
    if (gid >= nw) return;
    int word = perm ? perm[gid] : gid;
    int len  = lengths[word];
    float h[HID], x[EMBD], c[HID], hn[HID];
#pragma unroll
    for (int j = 0; j < HID; ++j) h[j] = 0.f;
#pragma unroll 1
    for (int j = 0; j < HID; ++j) c[j] = 0.f;
    const int* wch = chars + word * ml;
    float* op = out + (size_t)word * (2 * HID) + dir * HID;
#pragma unroll 1
    for (int t = 0; t < len; ++t) {
        int pos = dir ? (len - 1 - t) : t;
        int ch = wch[pos];
        const float2* ep = (const float2*)(emb + ch * EMBD);
#pragma unroll
        for (int k = 0; k < EMBD / 2; ++k) { float2 v = ep[k]; x[2*k] = v.x; x[2*k+1] = v.y; }
#pragma unroll 1
        for (int j = 0; j < HID; ++j) {
            const float4* wpt = sWU4 + j * 100;
            float4 bb = sB4[j];
            float gi = bb.x, gf = bb.y, gg = bb.z, go = bb.w;
#pragma unroll
            for (int k = 0; k < EMBD; ++k) {
                float4 w = wpt[k]; float xv = x[k];
                gi += w.x*xv; gf += w.y*xv; gg += w.z*xv; go += w.w*xv;
            }
#pragma unroll
            for (int k = 0; k < HID; ++k) {
                float4 w = wpt[EMBD + k]; float hv = h[k];
                gi += w.x*hv; gf += w.y*hv; gg += w.z*hv; go += w.w*hv;
            }
            float cn = sigm(gf) * c[j] + sigm(gi) * tanhfast(gg);
            c[j] = cn;
            hn[j] = sigm(go) * tanhfast(cn);
        }
#pragma unroll
        for (int j = 0; j < HID; ++j) h[j] = hn[j];
    }
#pragma unroll
    for (int j = 0; j < HID / 2; ++j)
        ((float2*)op)[j] = make_float2(h[2*j], h[2*j+1]);
}

extern "C" void kernel_launch(void* const* d_in, const int* in_sizes, int n_in,
                              void* d_out, int out_size, void* d_ws, size_t ws_size,
                              hipStream_t stream) {
    const int*   chars = (const int*)  d_in[0];
    const int*   lens  = (const int*)  d_in[1];
    const float* emb   = (const float*)d_in[2];
    const float* Wih_f = (const float*)d_in[3];
    const float* Whh_f = (const float*)d_in[4];
    const float* b_f   = (const float*)d_in[5];
    const float* Wih_b = (const float*)d_in[6];
    const float* Whh_b = (const float*)d_in[7];
    const float* b_b   = (const float*)d_in[8];
    float* out = (float*)d_out;

    const int nw    = in_sizes[1];
    const int ml    = in_sizes[0] / nw;
    const int vocab = in_sizes[2] / EMBD;

    size_t sortNeed = (size_t)(100 + nw) * 4;
    size_t embOff   = (sortNeed + 255) & ~(size_t)255;
    size_t embBytes = (size_t)vocab * 64 * 2;
    size_t wOff     = (embOff + embBytes + 1023) & ~(size_t)1023;
    size_t need     = wOff + (size_t)2 * NT * 2048 * 2;   // 106496 B

    int* ws = (int*)d_ws;
    bool haveSort = ws_size >= sortNeed;
    if (haveSort) {
        zero_counts_kernel<<<1, 128, 0, stream>>>(ws);
        hist_kernel<<<(nw + 255) / 256, 256, 0, stream>>>(lens, ws, nw);
        prefix_kernel<<<1, 1, 0, stream>>>(ws);
        scatter_kernel<<<(nw + 255) / 256, 256, 0, stream>>>(lens, ws, nw);
    }

    if (ws_size >= need && haveSort) {
        unsigned short* embp = (unsigned short*)((char*)d_ws + embOff);
        unsigned short* wpk  = (unsigned short*)((char*)d_ws + wOff);
        pack_emb_kernel<<<(vocab * 64 + 255) / 256, 256, 0, stream>>>(emb, embp, vocab);
        pack_w_kernel<<<(2 * NT * 2048 + 255) / 256, 256, 0, stream>>>(
            Wih_f, Whh_f, b_f, Wih_b, Whh_b, b_b, wpk);
        dim3 grid((nw + 63) / 64, 2);
        bilstm_mfma_kernel<<<grid, BLK, 0, stream>>>(chars, lens, ws + 100, embp, wpk,
                                                     out, nw, ml);
    } else {
        dim3 grid((nw + BLK - 1) / BLK, 2);
        bilstm_fallback_kernel<<<grid, BLK, 0, stream>>>(chars, lens, emb,
                                                         Wih_f, Whh_f, b_f,
                                                         Wih_b, Whh_b, b_b,
                                                         haveSort ? ws + 100 : nullptr,
                                                         out, nw, ml);
    }
}

// Round 16
// 485.070 us; speedup vs baseline: 2.6443x; 1.5745x over previous
//
#include <hip/hip_runtime.h>

#define EMBD 50
#define HID 50
#define BLK 256
#define NT 13               // gate tiles: 13*16 = 208 rows >= 200 real gates
#define LOG2E 1.44269504f

typedef float f32x4 __attribute__((ext_vector_type(4)));
typedef short short8 __attribute__((ext_vector_type(8)));
typedef unsigned u32x4 __attribute__((ext_vector_type(4)));

__device__ __forceinline__ int imax(int a, int b) { return a > b ? a : b; }
__device__ __forceinline__ int imin(int a, int b) { return a < b ? a : b; }

__device__ __forceinline__ unsigned short f2bf(float f) {
    unsigned u = __float_as_uint(f);
    u += 0x7FFFu + ((u >> 16) & 1u);
    return (unsigned short)(u >> 16);
}

// Native-instruction transcendentals. Gate inputs arrive PRESCALED:
// sigmoid args by log2e, tanh args by 2*log2e.
__device__ __forceinline__ float s2f(float x) {       // sigmoid(g), x = g*log2e
    return __builtin_amdgcn_rcpf(1.0f + __builtin_amdgcn_exp2f(-x));
}
__device__ __forceinline__ float t2f(float x) {       // tanh(g), x = g*2*log2e
    return 1.0f - 2.0f * __builtin_amdgcn_rcpf(__builtin_amdgcn_exp2f(x) + 1.0f);
}
__device__ __forceinline__ float tanhrt(float c) {    // tanh of runtime value
    return 1.0f - 2.0f * __builtin_amdgcn_rcpf(
        __builtin_amdgcn_exp2f((2.0f * LOG2E) * c) + 1.0f);
}
// pack two f32 -> u32 of 2 bf16 (lo = a, hi = b), single instruction
__device__ __forceinline__ unsigned cvtpk(float a, float b) {
    unsigned r;
    asm("v_cvt_pk_bf16_f32 %0, %1, %2" : "=v"(r) : "v"(a), "v"(b));
    return r;
}
// (fallback only)
__device__ __forceinline__ float sigm(float x) {
    return __fdividef(1.0f, 1.0f + __expf(-x));
}
__device__ __forceinline__ float tanhfast(float x) {
    float e = __expf(2.0f * x);
    return 1.0f - __fdividef(2.0f, e + 1.0f);
}

// ---------------- length bucket sort ----------------
// ws ints: [0,25) counts, [25,50) bases, [50,75) cursors, [100,100+NW) perm
__global__ void zero_counts_kernel(int* ws) {
    if (threadIdx.x < 75) ws[threadIdx.x] = 0;
}
// LDS-aggregated histogram: 25 global atomics per block instead of 256.
__global__ void hist_kernel(const int* __restrict__ lengths, int* ws, int nw) {
    __shared__ int lc[32];
    if (threadIdx.x < 32) lc[threadIdx.x] = 0;
    __syncthreads();
    int i = blockIdx.x * blockDim.x + threadIdx.x;
    if (i < nw) atomicAdd(&lc[lengths[i]], 1);
    __syncthreads();
    if (threadIdx.x < 25 && lc[threadIdx.x] > 0)
        atomicAdd(&ws[threadIdx.x], lc[threadIdx.x]);
}
__global__ void prefix_kernel(int* ws) {
    if (threadIdx.x == 0 && blockIdx.x == 0) {
        int acc = 0;
        for (int l = 0; l <= 24; ++l) { ws[25 + l] = acc; acc += ws[l]; }
    }
}
// LDS-aggregated scatter: block reserves per-bucket ranges with 25 atomics.
__global__ void scatter_kernel(const int* __restrict__ lengths, int* ws, int nw) {
    __shared__ int lcnt[32], lbase[32];
    if (threadIdx.x < 32) lcnt[threadIdx.x] = 0;
    __syncthreads();
    int i = blockIdx.x * blockDim.x + threadIdx.x;
    int l = 0, ticket = 0;
    bool act = i < nw;
    if (act) {
        l = lengths[i];
        ticket = atomicAdd(&lcnt[l], 1);
    }
    __syncthreads();
    if (threadIdx.x < 25 && lcnt[threadIdx.x] > 0)
        lbase[threadIdx.x] = atomicAdd(&ws[50 + threadIdx.x], lcnt[threadIdx.x]);
    __syncthreads();
    if (act) ws[100 + ws[25 + l] + lbase[l] + ticket] = i;
}

// ---------------- fused packing kernel ----------------
// tid < vocab*64: emb_pad[v][e] (e<50 emb, e==63 -> 1.0 bias lane, else 0)
// else: 13-tile weight pack (see R12 notes), prescaled (i,f,o: log2e; g: 2log2e)
__global__ void pack_all_kernel(const float* __restrict__ emb,
                                const float* __restrict__ Wih_f, const float* __restrict__ Whh_f,
                                const float* __restrict__ b_f,
                                const float* __restrict__ Wih_b, const float* __restrict__ Whh_b,
                                const float* __restrict__ b_b,
                                unsigned short* __restrict__ embp,
                                unsigned short* __restrict__ wp, int vocab) {
    int tid0 = blockIdx.x * blockDim.x + threadIdx.x;
    if (tid0 < vocab * 64) {
        int v = tid0 >> 6, e = tid0 & 63;
        float val = (e < EMBD) ? emb[v * EMBD + e] : (e == 63 ? 1.0f : 0.0f);
        embp[tid0] = f2bf(val);
        return;
    }
    int tid = tid0 - vocab * 64;
    if (tid >= 2 * NT * 2048) return;
    int i    = tid & 7;
    int lane = (tid >> 3) & 63;
    int kc   = (tid >> 9) & 3;
    int rem  = tid >> 11;
    int m    = rem % NT;
    int dir  = rem / NT;
    const float* Wih = dir ? Wih_b : Wih_f;
    const float* Whh = dir ? Whh_b : Whh_f;
    const float* bv  = dir ? b_b   : b_f;

    int p = lane & 15, grp = lane >> 4;
    int k = kc * 32 + 8 * grp + i;
    int s = p >> 2, q = p & 3;
    int cnt_s = (s < 2) ? 13 : 12;
    float val = 0.0f;
    if (m < cnt_s) {
        int j = 13 * s - (s == 3 ? 1 : 0) + m;
        int row = q * HID + j;
        if (k < 64) {
            if (k < EMBD)      val = Wih[row * EMBD + k];
            else if (k == 63)  val = bv[row];
        } else {
            int kk = k - 64;
            int half = kk >> 5;
            int s2 = (kk >> 3) & 3;
            int r = kk & 7;
            int mcol = half * 8 + r;
            int cnt2 = (s2 < 2) ? 13 : 12;
            if (mcol < cnt2) {
                int jc = 13 * s2 - (s2 == 3 ? 1 : 0) + mcol;
                val = Whh[row * HID + jc];
            }
        }
        val *= (q == 2) ? (2.0f * LOG2E) : LOG2E;
    }
    wp[tid] = f2bf(val);
}

// ---------------- main MFMA kernel: dual-stream (32 words/wave) ----------------
#define MFMA16(AW, BB, ACC) __builtin_amdgcn_mfma_f32_16x16x32_bf16((AW), (BB), (ACC), 0, 0, 0)
#define LDF(M, KC) (*(const short8*)(sWl + ((M) * 4 + (KC)) * 512))

// One tile, both streams: 4 shared fragment loads, 8 MFMAs (4 indep 2-chains),
// then gate nonlinearity per stream.
#define TTM2(M, CA, HA, CB, HB) {                                   \
    const short8 w0 = LDF(M,0), w2 = LDF(M,2);                      \
    const short8 w1 = LDF(M,1), w3 = LDF(M,3);                      \
    f32x4 xA = zz, hA_ = zz, xB = zz, hB_ = zz;                     \
    xA  = MFMA16(w0, cxA0, xA);  xB  = MFMA16(w0, cxB0, xB);        \
    hA_ = MFMA16(w2, bhA0, hA_); hB_ = MFMA16(w2, bhB0, hB_);       \
    xA  = MFMA16(w1, cxA1, xA);  xB  = MFMA16(w1, cxB1, xB);        \
    hA_ = MFMA16(w3, bhA1, hA_); hB_ = MFMA16(w3, bhB1, hB_);       \
    f32x4 aA = xA + hA_, aB = xB + hB_;                             \
    { float cn = s2f(aA[1]) * (CA) + s2f(aA[0]) * t2f(aA[2]);       \
      float hn = s2f(aA[3]) * tanhrt(cn);                           \
      (CA) = updA ? cn : (CA); (HA) = updA ? hn : (HA); }           \
    { float cn = s2f(aB[1]) * (CB) + s2f(aB[0]) * t2f(aB[2]);       \
      float hn = s2f(aB[3]) * tanhrt(cn);                           \
      (CB) = updB ? cn : (CB); (HB) = updB ? hn : (HB); } }

__global__ __launch_bounds__(BLK, 2)
void bilstm_mfma_kernel(const int* __restrict__ chars,
                        const int* __restrict__ lengths,
                        const int* __restrict__ perm,
                        const unsigned short* __restrict__ embp,
                        const unsigned short* __restrict__ wp,
                        float* __restrict__ out, int nw, int ml)
{
    const int dir = blockIdx.y;
    __shared__ unsigned short sW[NT * 4 * 512];   // 52 KB of A-fragments
    {
        const float4* src = (const float4*)(wp + dir * (NT * 4 * 512));
        float4* dst = (float4*)sW;
        for (int i = threadIdx.x; i < NT * 4 * 512 / 8; i += BLK) dst[i] = src[i];
    }
    __syncthreads();

    const int lane = threadIdx.x & 63;
    const int wv   = threadIdx.x >> 6;
    const int wcol = lane & 15;          // word column
    const int s    = lane >> 4;          // lane group

    int base = (blockIdx.x * 4 + wv) * 32;
    int giA = imin(base + wcol, nw - 1);
    int giB = imin(base + 16 + wcol, nw - 1);
    const int wordA = perm[giA];
    const int wordB = perm[giB];
    const int lenA  = lengths[wordA];
    const int lenB  = lengths[wordB];

    int lmax = imax(lenA, lenB);
    lmax = imax(lmax, __shfl_xor(lmax, 1));
    lmax = imax(lmax, __shfl_xor(lmax, 2));
    lmax = imax(lmax, __shfl_xor(lmax, 4));
    lmax = imax(lmax, __shfl_xor(lmax, 8));

    const int* charpA = chars + (size_t)wordA * ml;
    const int* charpB = chars + (size_t)wordB * ml;
    const unsigned short* sWl = sW + lane * 8;

    const f32x4 zz = {0.0f, 0.0f, 0.0f, 0.0f};
    float cA00=0,cA01=0,cA02=0,cA03=0,cA04=0,cA05=0,cA06=0,cA07=0,cA08=0,cA09=0,cA10=0,cA11=0,cA12=0;
    float hA00=0,hA01=0,hA02=0,hA03=0,hA04=0,hA05=0,hA06=0,hA07=0,hA08=0,hA09=0,hA10=0,hA11=0,hA12=0;
    float cB00=0,cB01=0,cB02=0,cB03=0,cB04=0,cB05=0,cB06=0,cB07=0,cB08=0,cB09=0,cB10=0,cB11=0,cB12=0;
    float hB00=0,hB01=0,hB02=0,hB03=0,hB04=0,hB05=0,hB06=0,hB07=0,hB08=0,hB09=0,hB10=0,hB11=0,hB12=0;
    short8 bhA0, bhA1, bhB0, bhB1;
#pragma unroll
    for (int i2 = 0; i2 < 8; ++i2) { bhA0[i2]=0; bhA1[i2]=0; bhB0[i2]=0; bhB1[i2]=0; }

    // prefetch x for t=0
    short8 cxA0, cxA1, cxB0, cxB1;
    if (lmax > 0) {
        int pA = dir ? imax(lenA - 1, 0) : 0;
        int pB = dir ? imax(lenB - 1, 0) : 0;
        int chA = charpA[pA], chB = charpB[pB];
        cxA0 = *(const short8*)(embp + chA * 64 + 8 * s);
        cxA1 = *(const short8*)(embp + chA * 64 + 32 + 8 * s);
        cxB0 = *(const short8*)(embp + chB * 64 + 8 * s);
        cxB1 = *(const short8*)(embp + chB * 64 + 32 + 8 * s);
    }

    for (int t = 0; t < lmax; ++t) {
        // prefetch next step's x (latency hides under the MFMA blocks)
        int tn = (t + 1 < lmax) ? t + 1 : t;
        int pA = dir ? imax(lenA - 1 - tn, 0) : imin(tn, imax(lenA - 1, 0));
        int pB = dir ? imax(lenB - 1 - tn, 0) : imin(tn, imax(lenB - 1, 0));
        int chA = charpA[pA], chB = charpB[pB];
        short8 nA0 = *(const short8*)(embp + chA * 64 + 8 * s);
        short8 nA1 = *(const short8*)(embp + chA * 64 + 32 + 8 * s);
        short8 nB0 = *(const short8*)(embp + chB * 64 + 8 * s);
        short8 nB1 = *(const short8*)(embp + chB * 64 + 32 + 8 * s);

        const bool updA = (t < lenA);
        const bool updB = (t < lenB);
        // bh* hold PREVIOUS h throughout; rebuilt after all tiles.
        TTM2(0,  cA00, hA00, cB00, hB00)
        TTM2(1,  cA01, hA01, cB01, hB01)
        TTM2(2,  cA02, hA02, cB02, hB02)
        TTM2(3,  cA03, hA03, cB03, hB03)
        TTM2(4,  cA04, hA04, cB04, hB04)
        TTM2(5,  cA05, hA05, cB05, hB05)
        TTM2(6,  cA06, hA06, cB06, hB06)
        TTM2(7,  cA07, hA07, cB07, hB07)
        TTM2(8,  cA08, hA08, cB08, hB08)
        TTM2(9,  cA09, hA09, cB09, hB09)
        TTM2(10, cA10, hA10, cB10, hB10)
        TTM2(11, cA11, hA11, cB11, hB11)
        TTM2(12, cA12, hA12, cB12, hB12)

        // repack h -> bf16 B-fragments via v_cvt_pk_bf16_f32.
        // bh?1 lanes [5..7] stay 0: those k-slots have all-zero weight cols.
        u32x4 p0, p1;
        p0[0] = cvtpk(hA00, hA01); p0[1] = cvtpk(hA02, hA03);
        p0[2] = cvtpk(hA04, hA05); p0[3] = cvtpk(hA06, hA07);
        p1[0] = cvtpk(hA08, hA09); p1[1] = cvtpk(hA10, hA11);
        p1[2] = cvtpk(hA12, 0.0f); p1[3] = 0u;
        bhA0 = __builtin_bit_cast(short8, p0);
        bhA1 = __builtin_bit_cast(short8, p1);
        p0[0] = cvtpk(hB00, hB01); p0[1] = cvtpk(hB02, hB03);
        p0[2] = cvtpk(hB04, hB05); p0[3] = cvtpk(hB06, hB07);
        p1[0] = cvtpk(hB08, hB09); p1[1] = cvtpk(hB10, hB11);
        p1[2] = cvtpk(hB12, 0.0f); p1[3] = 0u;
        bhB0 = __builtin_bit_cast(short8, p0);
        bhB1 = __builtin_bit_cast(short8, p1);

        cxA0 = nA0; cxA1 = nA1; cxB0 = nB0; cxB1 = nB1;
    }

    // lane's j range: [off(s), off(s)+cnt(s)), contiguous
    int offs = 13 * s - (s == 3 ? 1 : 0);
    float* oA = out + (size_t)wordA * (2 * HID) + dir * HID + offs;
    oA[0] = hA00; oA[1] = hA01; oA[2]  = hA02; oA[3]  = hA03;
    oA[4] = hA04; oA[5] = hA05; oA[6]  = hA06; oA[7]  = hA07;
    oA[8] = hA08; oA[9] = hA09; oA[10] = hA10; oA[11] = hA11;
    if (s < 2) oA[12] = hA12;
    float* oB = out + (size_t)wordB * (2 * HID) + dir * HID + offs;
    oB[0] = hB00; oB[1] = hB01; oB[2]  = hB02; oB[3]  = hB03;
    oB[4] = hB04; oB[5] = hB05; oB[6]  = hB06; oB[7]  = hB07;
    oB[8] = hB08; oB[9] = hB09; oB[10] = hB10; oB[11] = hB11;
    if (s < 2) oB[12] = hB12;
}

// ---------------- R1 fallback (scalar f32) ----------------
__global__ __launch_bounds__(BLK, 2)
void bilstm_fallback_kernel(const int* __restrict__ chars,
                            const int* __restrict__ lengths,
                            const float* __restrict__ emb,
                            const float* __restrict__ Wih_f, const float* __restrict__ Whh_f, const float* __restrict__ b_f,
                            const float* __restrict__ Wih_b, const float* __restrict__ Whh_b, const float* __restrict__ b_b,
                            const int* __restrict__ perm,
                            float* __restrict__ out, int nw, int ml)
{
    const int dir = blockIdx.y;
    const float* Wih = dir ? Wih_b : Wih_f;
    const float* Whh = dir ? Whh_b : Whh_f;
    const float* bv  = dir ? b_b  : b_f;
    __shared__ float4 sWU4[HID * 100];
    __shared__ float4 sB4[HID];
    {
        float* p = (float*)sWU4;
        for (int i = threadIdx.x; i < HID * 100 * 4; i += BLK) {
            int g = i & 3, r = i >> 2, j = r / 100, k = r - j * 100;
            p[i] = (k < EMBD) ? Wih[(j + g * HID) * EMBD + k]
                              : Whh[(j + g * HID) * HID + (k - EMBD)];
        }
        if (threadIdx.x < HID) {
            int j = threadIdx.x;
            sB4[j] = make_float4(bv[j], bv[j + HID], bv[j + 2*HID], bv[j + 3*HID]);
        }
    }
    __syncthreads();
    int gid = blockIdx.x * BLK + threadIdx.x;
    if (gid >= nw) return;
    int word = perm ? perm[gid] : gid;
    int len  = lengths[word];
    float h[HID], x[EMBD], c[HID], hn[HID];
#pragma unroll
    for (int j = 0; j < HID; ++j) h[j] = 0.f;
#pragma unroll 1
    for (int j = 0; j < HID; ++j) c[j] = 0.f;
    const int* wch = chars + word * ml;
    float* op = out + (size_t)word * (2 * HID) + dir * HID;
#pragma unroll 1
    for (int t = 0; t < len; ++t) {
        int pos = dir ? (len - 1 - t) : t;
        int ch = wch[pos];
        const float2* ep = (const float2*)(emb + ch * EMBD);
#pragma unroll
        for (int k = 0; k < EMBD / 2; ++k) { float2 v = ep[k]; x[2*k] = v.x; x[2*k+1] = v.y; }
#pragma unroll 1
        for (int j = 0; j < HID; ++j) {
            const float4* wpt = sWU4 + j * 100;
            float4 bb = sB4[j];
            float gi = bb.x, gf = bb.y, gg = bb.z, go = bb.w;
#pragma unroll
            for (int k = 0; k < EMBD; ++k) {
                float4 w = wpt[k]; float xv = x[k];
                gi += w.x*xv; gf += w.y*xv; gg += w.z*xv; go += w.w*xv;
            }
#pragma unroll
            for (int k = 0; k < HID; ++k) {
                float4 w = wpt[EMBD + k]; float hv = h[k];
                gi += w.x*hv; gf += w.y*hv; gg += w.z*hv; go += w.w*hv;
            }
            float cn = sigm(gf) * c[j] + sigm(gi) * tanhfast(gg);
            c[j] = cn;
            hn[j] = sigm(go) * tanhfast(cn);
        }
#pragma unroll
        for (int j = 0; j < HID; ++j) h[j] = hn[j];
    }
#pragma unroll
    for (int j = 0; j < HID / 2; ++j)
        ((float2*)op)[j] = make_float2(h[2*j], h[2*j+1]);
}

extern "C" void kernel_launch(void* const* d_in, const int* in_sizes, int n_in,
                              void* d_out, int out_size, void* d_ws, size_t ws_size,
                              hipStream_t stream) {
    const int*   chars = (const int*)  d_in[0];
    const int*   lens  = (const int*)  d_in[1];
    const float* emb   = (const float*)d_in[2];
    const float* Wih_f = (const float*)d_in[3];
    const float* Whh_f = (const float*)d_in[4];
    const float* b_f   = (const float*)d_in[5];
    const float* Wih_b = (const float*)d_in[6];
    const float* Whh_b = (const float*)d_in[7];
    const float* b_b   = (const float*)d_in[8];
    float* out = (float*)d_out;

    const int nw    = in_sizes[1];
    const int ml    = in_sizes[0] / nw;
    const int vocab = in_sizes[2] / EMBD;

    size_t sortNeed = (size_t)(100 + nw) * 4;
    size_t embOff   = (sortNeed + 255) & ~(size_t)255;
    size_t embBytes = (size_t)vocab * 64 * 2;
    size_t wOff     = (embOff + embBytes + 1023) & ~(size_t)1023;
    size_t need     = wOff + (size_t)2 * NT * 2048 * 2;   // 106496 B

    int* ws = (int*)d_ws;
    bool haveSort = ws_size >= sortNeed;
    if (haveSort) {
        zero_counts_kernel<<<1, 128, 0, stream>>>(ws);
        hist_kernel<<<(nw + 255) / 256, 256, 0, stream>>>(lens, ws, nw);
        prefix_kernel<<<1, 1, 0, stream>>>(ws);
        scatter_kernel<<<(nw + 255) / 256, 256, 0, stream>>>(lens, ws, nw);
    }

    if (ws_size >= need && haveSort) {
        unsigned short* embp = (unsigned short*)((char*)d_ws + embOff);
        unsigned short* wpk  = (unsigned short*)((char*)d_ws + wOff);
        int packTot = vocab * 64 + 2 * NT * 2048;
        pack_all_kernel<<<(packTot + 255) / 256, 256, 0, stream>>>(
            emb, Wih_f, Whh_f, b_f, Wih_b, Whh_b, b_b, embp, wpk, vocab);
        dim3 grid((nw + 127) / 128, 2);
        bilstm_mfma_kernel<<<grid, BLK, 0, stream>>>(chars, lens, ws + 100, embp, wpk,
                                                     out, nw, ml);
    } else {
        dim3 grid((nw + BLK - 1) / BLK, 2);
        bilstm_fallback_kernel<<<grid, BLK, 0, stream>>>(chars, lens, emb,
                                                         Wih_f, Whh_f, b_f,
                                                         Wih_b, Whh_b, b_b,
                                                         haveSort ? ws + 100 : nullptr,
                                                         out, nw, ml);
    }
}

// Round 17
// 296.606 us; speedup vs baseline: 4.3245x; 1.6354x over previous
//
#include <hip/hip_runtime.h>

#define EMBD 50
#define HID 50
#define BLK 256
#define NT 13               // gate tiles: 13*16 = 208 rows >= 200 real gates
#define LOG2E 1.44269504f

typedef float f32x4 __attribute__((ext_vector_type(4)));
typedef short short8 __attribute__((ext_vector_type(8)));
typedef unsigned u32x4 __attribute__((ext_vector_type(4)));

__device__ __forceinline__ int imax(int a, int b) { return a > b ? a : b; }
__device__ __forceinline__ int imin(int a, int b) { return a < b ? a : b; }

__device__ __forceinline__ unsigned short f2bf(float f) {
    unsigned u = __float_as_uint(f);
    u += 0x7FFFu + ((u >> 16) & 1u);
    return (unsigned short)(u >> 16);
}

// Native-instruction transcendentals. Gate inputs arrive PRESCALED:
// sigmoid args by log2e, tanh args by 2*log2e.
__device__ __forceinline__ float s2f(float x) {       // sigmoid(g), x = g*log2e
    return __builtin_amdgcn_rcpf(1.0f + __builtin_amdgcn_exp2f(-x));
}
__device__ __forceinline__ float t2f(float x) {       // tanh(g), x = g*2*log2e
    return 1.0f - 2.0f * __builtin_amdgcn_rcpf(__builtin_amdgcn_exp2f(x) + 1.0f);
}
__device__ __forceinline__ float tanhrt(float c) {    // tanh of runtime value
    return 1.0f - 2.0f * __builtin_amdgcn_rcpf(
        __builtin_amdgcn_exp2f((2.0f * LOG2E) * c) + 1.0f);
}
// pack two f32 -> u32 of 2 bf16 (lo = a, hi = b), single instruction
__device__ __forceinline__ unsigned cvtpk(float a, float b) {
    unsigned r;
    asm("v_cvt_pk_bf16_f32 %0, %1, %2" : "=v"(r) : "v"(a), "v"(b));
    return r;
}
// (fallback only)
__device__ __forceinline__ float sigm(float x) {
    return __fdividef(1.0f, 1.0f + __expf(-x));
}
__device__ __forceinline__ float tanhfast(float x) {
    float e = __expf(2.0f * x);
    return 1.0f - __fdividef(2.0f, e + 1.0f);
}

// ---------------- length bucket sort ----------------
// ws ints: [0,25) counts, [25,50) bases, [50,75) cursors, [100,100+NW) perm
__global__ void zero_counts_kernel(int* ws) {
    if (threadIdx.x < 75) ws[threadIdx.x] = 0;
}
// LDS-aggregated histogram: 25 global atomics per block instead of 256.
__global__ void hist_kernel(const int* __restrict__ lengths, int* ws, int nw) {
    __shared__ int lc[32];
    if (threadIdx.x < 32) lc[threadIdx.x] = 0;
    __syncthreads();
    int i = blockIdx.x * blockDim.x + threadIdx.x;
    if (i < nw) atomicAdd(&lc[lengths[i]], 1);
    __syncthreads();
    if (threadIdx.x < 25 && lc[threadIdx.x] > 0)
        atomicAdd(&ws[threadIdx.x], lc[threadIdx.x]);
}
__global__ void prefix_kernel(int* ws) {
    if (threadIdx.x == 0 && blockIdx.x == 0) {
        int acc = 0;
        for (int l = 0; l <= 24; ++l) { ws[25 + l] = acc; acc += ws[l]; }
    }
}
// LDS-aggregated scatter: block reserves per-bucket ranges with 25 atomics.
__global__ void scatter_kernel(const int* __restrict__ lengths, int* ws, int nw) {
    __shared__ int lcnt[32], lbase[32];
    if (threadIdx.x < 32) lcnt[threadIdx.x] = 0;
    __syncthreads();
    int i = blockIdx.x * blockDim.x + threadIdx.x;
    int l = 0, ticket = 0;
    bool act = i < nw;
    if (act) {
        l = lengths[i];
        ticket = atomicAdd(&lcnt[l], 1);
    }
    __syncthreads();
    if (threadIdx.x < 25 && lcnt[threadIdx.x] > 0)
        lbase[threadIdx.x] = atomicAdd(&ws[50 + threadIdx.x], lcnt[threadIdx.x]);
    __syncthreads();
    if (act) ws[100 + ws[25 + l] + lbase[l] + ticket] = i;
}

// ---------------- fused packing kernel ----------------
// tid < vocab*64: emb_pad[v][e] (e<50 emb, e==63 -> 1.0 bias lane, else 0)
// else: 13-tile weight pack (see R12 notes), prescaled (i,f,o: log2e; g: 2log2e)
__global__ void pack_all_kernel(const float* __restrict__ emb,
                                const float* __restrict__ Wih_f, const float* __restrict__ Whh_f,
                                const float* __restrict__ b_f,
                                const float* __restrict__ Wih_b, const float* __restrict__ Whh_b,
                                const float* __restrict__ b_b,
                                unsigned short* __restrict__ embp,
                                unsigned short* __restrict__ wp, int vocab) {
    int tid0 = blockIdx.x * blockDim.x + threadIdx.x;
    if (tid0 < vocab * 64) {
        int v = tid0 >> 6, e = tid0 & 63;
        float val = (e < EMBD) ? emb[v * EMBD + e] : (e == 63 ? 1.0f : 0.0f);
        embp[tid0] = f2bf(val);
        return;
    }
    int tid = tid0 - vocab * 64;
    if (tid >= 2 * NT * 2048) return;
    int i    = tid & 7;
    int lane = (tid >> 3) & 63;
    int kc   = (tid >> 9) & 3;
    int rem  = tid >> 11;
    int m    = rem % NT;
    int dir  = rem / NT;
    const float* Wih = dir ? Wih_b : Wih_f;
    const float* Whh = dir ? Whh_b : Whh_f;
    const float* bv  = dir ? b_b   : b_f;

    int p = lane & 15, grp = lane >> 4;
    int k = kc * 32 + 8 * grp + i;
    int s = p >> 2, q = p & 3;
    int cnt_s = (s < 2) ? 13 : 12;
    float val = 0.0f;
    if (m < cnt_s) {
        int j = 13 * s - (s == 3 ? 1 : 0) + m;
        int row = q * HID + j;
        if (k < 64) {
            if (k < EMBD)      val = Wih[row * EMBD + k];
            else if (k == 63)  val = bv[row];
        } else {
            int kk = k - 64;
            int half = kk >> 5;
            int s2 = (kk >> 3) & 3;
            int r = kk & 7;
            int mcol = half * 8 + r;
            int cnt2 = (s2 < 2) ? 13 : 12;
            if (mcol < cnt2) {
                int jc = 13 * s2 - (s2 == 3 ? 1 : 0) + mcol;
                val = Whh[row * HID + jc];
            }
        }
        val *= (q == 2) ? (2.0f * LOG2E) : LOG2E;
    }
    wp[tid] = f2bf(val);
}

// ---------------- main MFMA kernel (R14 single-stream) ----------------
__device__ __forceinline__ f32x4 mf(const unsigned short* sWl, int m, int kc,
                                    short8 bb, f32x4 acc) {
    const short8 aw = *(const short8*)(sWl + (m * 4 + kc) * 512);
    return __builtin_amdgcn_mfma_f32_16x16x32_bf16(aw, bb, acc, 0, 0, 0);
}

// One j-element per lane per tile. Two independent 2-deep MFMA chains (x-part
// and h-part) summed at the end.
#define TTM(M, C, H) {                                      \
    f32x4 ax = zz, ah = zz;                                 \
    ax = mf(sWl, (M), 0, cx0, ax);                          \
    ah = mf(sWl, (M), 2, bh0, ah);                          \
    ax = mf(sWl, (M), 1, cx1, ax);                          \
    ah = mf(sWl, (M), 3, bh1, ah);                          \
    f32x4 ac = ax + ah;                                     \
    float cn = s2f(ac[1]) * (C) + s2f(ac[0]) * t2f(ac[2]);  \
    float hn = s2f(ac[3]) * tanhrt(cn);                     \
    (C) = upd ? cn : (C);                                   \
    (H) = upd ? hn : (H); }

__global__ __launch_bounds__(BLK, 2)
void bilstm_mfma_kernel(const int* __restrict__ chars,
                        const int* __restrict__ lengths,
                        const int* __restrict__ perm,
                        const unsigned short* __restrict__ embp,
                        const unsigned short* __restrict__ wp,
                        float* __restrict__ out, int nw, int ml)
{
    const int dir = blockIdx.y;
    __shared__ unsigned short sW[NT * 4 * 512];   // 52 KB of A-fragments
    {
        const float4* src = (const float4*)(wp + dir * (NT * 4 * 512));
        float4* dst = (float4*)sW;
        for (int i = threadIdx.x; i < NT * 4 * 512 / 8; i += BLK) dst[i] = src[i];
    }
    __syncthreads();

    const int lane = threadIdx.x & 63;
    const int wv   = threadIdx.x >> 6;
    const int wcol = lane & 15;          // word column
    const int s    = lane >> 4;          // lane group

    int gidx = (blockIdx.x * 4 + wv) * 16 + wcol;
    gidx = imin(gidx, nw - 1);
    const int word = perm[gidx];
    const int len  = lengths[word];

    int lmax = len;
    lmax = imax(lmax, __shfl_xor(lmax, 1));
    lmax = imax(lmax, __shfl_xor(lmax, 2));
    lmax = imax(lmax, __shfl_xor(lmax, 4));
    lmax = imax(lmax, __shfl_xor(lmax, 8));

    const int* charp = chars + (size_t)word * ml;
    const unsigned short* sWl = sW + lane * 8;

    const f32x4 zz = {0.0f, 0.0f, 0.0f, 0.0f};
    float c00=0,c01=0,c02=0,c03=0,c04=0,c05=0,c06=0,c07=0,c08=0,c09=0,c10=0,c11=0,c12=0;
    float h00=0,h01=0,h02=0,h03=0,h04=0,h05=0,h06=0,h07=0,h08=0,h09=0,h10=0,h11=0,h12=0;
    short8 bh0, bh1;
#pragma unroll
    for (int i2 = 0; i2 < 8; ++i2) { bh0[i2] = 0; bh1[i2] = 0; }

    // prefetch x for t=0
    short8 cx0, cx1;
    if (lmax > 0) {
        int pos0 = dir ? imax(len - 1, 0) : 0;
        int ch = charp[pos0];
        cx0 = *(const short8*)(embp + ch * 64 + 8 * s);
        cx1 = *(const short8*)(embp + ch * 64 + 32 + 8 * s);
    }

    for (int t = 0; t < lmax; ++t) {
        // prefetch next step's x (latency hides under the MFMA blocks)
        int tn = (t + 1 < lmax) ? t + 1 : t;
        int posn = dir ? imax(len - 1 - tn, 0) : tn;
        int chn = charp[posn];
        short8 nx0 = *(const short8*)(embp + chn * 64 + 8 * s);
        short8 nx1 = *(const short8*)(embp + chn * 64 + 32 + 8 * s);

        const bool upd = (t < len);
        // bh0/bh1 hold PREVIOUS h throughout; rebuilt after all tiles.
        TTM(0,  c00, h00)
        TTM(1,  c01, h01)
        TTM(2,  c02, h02)
        TTM(3,  c03, h03)
        TTM(4,  c04, h04)
        TTM(5,  c05, h05)
        TTM(6,  c06, h06)
        TTM(7,  c07, h07)
        TTM(8,  c08, h08)
        TTM(9,  c09, h09)
        TTM(10, c10, h10)
        TTM(11, c11, h11)
        TTM(12, c12, h12)

        // repack h -> bf16 B-fragments via v_cvt_pk_bf16_f32 (7 instrs).
        // bh1[5..7] stay 0: those k-slots have all-zero weight columns.
        u32x4 p0, p1;
        p0[0] = cvtpk(h00, h01); p0[1] = cvtpk(h02, h03);
        p0[2] = cvtpk(h04, h05); p0[3] = cvtpk(h06, h07);
        p1[0] = cvtpk(h08, h09); p1[1] = cvtpk(h10, h11);
        p1[2] = cvtpk(h12, 0.0f); p1[3] = 0u;
        bh0 = __builtin_bit_cast(short8, p0);
        bh1 = __builtin_bit_cast(short8, p1);

        cx0 = nx0; cx1 = nx1;
    }

    // lane's j range: [off(s), off(s)+cnt(s)), contiguous
    int offs = 13 * s - (s == 3 ? 1 : 0);
    float* outw = out + (size_t)word * (2 * HID) + dir * HID + offs;
    outw[0] = h00; outw[1] = h01; outw[2]  = h02; outw[3]  = h03;
    outw[4] = h04; outw[5] = h05; outw[6]  = h06; outw[7]  = h07;
    outw[8] = h08; outw[9] = h09; outw[10] = h10; outw[11] = h11;
    if (s < 2) outw[12] = h12;   // pad element for s>=2
}

// ---------------- R1 fallback (scalar f32) ----------------
__global__ __launch_bounds__(BLK, 2)
void bilstm_fallback_kernel(const int* __restrict__ chars,
                            const int* __restrict__ lengths,
                            const float* __restrict__ emb,
                            const float* __restrict__ Wih_f, const float* __restrict__ Whh_f, const float* __restrict__ b_f,
                            const float* __restrict__ Wih_b, const float* __restrict__ Whh_b, const float* __restrict__ b_b,
                            const int* __restrict__ perm,
                            float* __restrict__ out, int nw, int ml)
{
    const int dir = blockIdx.y;
    const float* Wih = dir ? Wih_b : Wih_f;
    const float* Whh = dir ? Whh_b : Whh_f;
    const float* bv  = dir ? b_b  : b_f;
    __shared__ float4 sWU4[HID * 100];
    __shared__ float4 sB4[HID];
    {
        float* p = (float*)sWU4;
        for (int i = threadIdx.x; i < HID * 100 * 4; i += BLK) {
            int g = i & 3, r = i >> 2, j = r / 100, k = r - j * 100;
            p[i] = (k < EMBD) ? Wih[(j + g * HID) * EMBD + k]
                              : Whh[(j + g * HID) * HID + (k - EMBD)];
        }
        if (threadIdx.x < HID) {
            int j = threadIdx.x;
            sB4[j] = make_float4(bv[j], bv[j + HID], bv[j + 2*HID], bv[j + 3*HID]);
        }
    }
    __syncthreads();
    int gid = blockIdx.x * BLK + threadIdx.x;
    if (gid >= nw) return;
    int word = perm ? perm[gid] : gid;
    int len  = lengths[word];
    float h[HID], x[EMBD], c[HID], hn[HID];
#pragma unroll
    for (int j = 0; j < HID; ++j) h[j] = 0.f;
#pragma unroll 1
    for (int j = 0; j < HID; ++j) c[j] = 0.f;
    const int* wch = chars + word * ml;
    float* op = out + (size_t)word * (2 * HID) + dir * HID;
#pragma unroll 1
    for (int t = 0; t < len; ++t) {
        int pos = dir ? (len - 1 - t) : t;
        int ch = wch[pos];
        const float2* ep = (const float2*)(emb + ch * EMBD);
#pragma unroll
        for (int k = 0; k < EMBD / 2; ++k) { float2 v = ep[k]; x[2*k] = v.x; x[2*k+1] = v.y; }
#pragma unroll 1
        for (int j = 0; j < HID; ++j) {
            const float4* wpt = sWU4 + j * 100;
            float4 bb = sB4[j];
            float gi = bb.x, gf = bb.y, gg = bb.z, go = bb.w;
#pragma unroll
            for (int k = 0; k < EMBD; ++k) {
                float4 w = wpt[k]; float xv = x[k];
                gi += w.x*xv; gf += w.y*xv; gg += w.z*xv; go += w.w*xv;
            }
#pragma unroll
            for (int k = 0; k < HID; ++k) {
                float4 w = wpt[EMBD + k]; float hv = h[k];
                gi += w.x*hv; gf += w.y*hv; gg += w.z*hv; go += w.w*hv;
            }
            float cn = sigm(gf) * c[j] + sigm(gi) * tanhfast(gg);
            c[j] = cn;
            hn[j] = sigm(go) * tanhfast(cn);
        }
#pragma unroll
        for (int j = 0; j < HID; ++j) h[j] = hn[j];
    }
#pragma unroll
    for (int j = 0; j < HID / 2; ++j)
        ((float2*)op)[j] = make_float2(h[2*j], h[2*j+1]);
}

extern "C" void kernel_launch(void* const* d_in, const int* in_sizes, int n_in,
                              void* d_out, int out_size, void* d_ws, size_t ws_size,
                              hipStream_t stream) {
    const int*   chars = (const int*)  d_in[0];
    const int*   lens  = (const int*)  d_in[1];
    const float* emb   = (const float*)d_in[2];
    const float* Wih_f = (const float*)d_in[3];
    const float* Whh_f = (const float*)d_in[4];
    const float* b_f   = (const float*)d_in[5];
    const float* Wih_b = (const float*)d_in[6];
    const float* Whh_b = (const float*)d_in[7];
    const float* b_b   = (const float*)d_in[8];
    float* out = (float*)d_out;

    const int nw    = in_sizes[1];
    const int ml    = in_sizes[0] / nw;
    const int vocab = in_sizes[2] / EMBD;

    size_t sortNeed = (size_t)(100 + nw) * 4;
    size_t embOff   = (sortNeed + 255) & ~(size_t)255;
    size_t embBytes = (size_t)vocab * 64 * 2;
    size_t wOff     = (embOff + embBytes + 1023) & ~(size_t)1023;
    size_t need     = wOff + (size_t)2 * NT * 2048 * 2;   // 106496 B

    int* ws = (int*)d_ws;
    bool haveSort = ws_size >= sortNeed;
    if (haveSort) {
        zero_counts_kernel<<<1, 128, 0, stream>>>(ws);
        hist_kernel<<<(nw + 255) / 256, 256, 0, stream>>>(lens, ws, nw);
        prefix_kernel<<<1, 1, 0, stream>>>(ws);
        scatter_kernel<<<(nw + 255) / 256, 256, 0, stream>>>(lens, ws, nw);
    }

    if (ws_size >= need && haveSort) {
        unsigned short* embp = (unsigned short*)((char*)d_ws + embOff);
        unsigned short* wpk  = (unsigned short*)((char*)d_ws + wOff);
        int packTot = vocab * 64 + 2 * NT * 2048;
        pack_all_kernel<<<(packTot + 255) / 256, 256, 0, stream>>>(
            emb, Wih_f, Whh_f, b_f, Wih_b, Whh_b, b_b, embp, wpk, vocab);
        dim3 grid((nw + 63) / 64, 2);
        bilstm_mfma_kernel<<<grid, BLK, 0, stream>>>(chars, lens, ws + 100, embp, wpk,
                                                     out, nw, ml);
    } else {
        dim3 grid((nw + BLK - 1) / BLK, 2);
        bilstm_fallback_kernel<<<grid, BLK, 0, stream>>>(chars, lens, emb,
                                                         Wih_f, Whh_f, b_f,
                                                         Wih_b, Whh_b, b_b,
                                                         haveSort ? ws + 100 : nullptr,
                                                         out, nw, ml);
    }
}

// Round 18
// 240.819 us; speedup vs baseline: 5.3263x; 1.2317x over previous
//
#include <hip/hip_runtime.h>

#define EMBD 50
#define HID 50
#define BLK 256
#define NT 13               // gate tiles: 13*16 = 208 rows >= 200 real gates
#define LOG2E 1.44269504f

typedef float f32x4 __attribute__((ext_vector_type(4)));
typedef short short8 __attribute__((ext_vector_type(8)));
typedef unsigned u32x4 __attribute__((ext_vector_type(4)));

__device__ __forceinline__ int imax(int a, int b) { return a > b ? a : b; }
__device__ __forceinline__ int imin(int a, int b) { return a < b ? a : b; }

__device__ __forceinline__ unsigned short f2bf(float f) {
    unsigned u = __float_as_uint(f);
    u += 0x7FFFu + ((u >> 16) & 1u);
    return (unsigned short)(u >> 16);
}

// Native-instruction transcendentals. Gate inputs arrive PRESCALED:
// sigmoid args by log2e, tanh args by 2*log2e.
__device__ __forceinline__ float s2f(float x) {
    return __builtin_amdgcn_rcpf(1.0f + __builtin_amdgcn_exp2f(-x));
}
__device__ __forceinline__ float t2f(float x) {
    return 1.0f - 2.0f * __builtin_amdgcn_rcpf(__builtin_amdgcn_exp2f(x) + 1.0f);
}
__device__ __forceinline__ float tanhrt(float c) {
    return 1.0f - 2.0f * __builtin_amdgcn_rcpf(
        __builtin_amdgcn_exp2f((2.0f * LOG2E) * c) + 1.0f);
}
__device__ __forceinline__ unsigned cvtpk(float a, float b) {
    unsigned r;
    asm("v_cvt_pk_bf16_f32 %0, %1, %2" : "=v"(r) : "v"(a), "v"(b));
    return r;
}
// (fallback only)
__device__ __forceinline__ float sigm(float x) {
    return __fdividef(1.0f, 1.0f + __expf(-x));
}
__device__ __forceinline__ float tanhfast(float x) {
    float e = __expf(2.0f * x);
    return 1.0f - __fdividef(2.0f, e + 1.0f);
}

// ---------------- length bucket sort ----------------
__global__ void zero_counts_kernel(int* ws) {
    if (threadIdx.x < 75) ws[threadIdx.x] = 0;
}
__global__ void hist_kernel(const int* __restrict__ lengths, int* ws, int nw) {
    __shared__ int lc[32];
    if (threadIdx.x < 32) lc[threadIdx.x] = 0;
    __syncthreads();
    int i = blockIdx.x * blockDim.x + threadIdx.x;
    if (i < nw) atomicAdd(&lc[lengths[i]], 1);
    __syncthreads();
    if (threadIdx.x < 25 && lc[threadIdx.x] > 0)
        atomicAdd(&ws[threadIdx.x], lc[threadIdx.x]);
}
__global__ void prefix_kernel(int* ws) {
    if (threadIdx.x == 0 && blockIdx.x == 0) {
        int acc = 0;
        for (int l = 0; l <= 24; ++l) { ws[25 + l] = acc; acc += ws[l]; }
    }
}
__global__ void scatter_kernel(const int* __restrict__ lengths, int* ws, int nw) {
    __shared__ int lcnt[32], lbase[32];
    if (threadIdx.x < 32) lcnt[threadIdx.x] = 0;
    __syncthreads();
    int i = blockIdx.x * blockDim.x + threadIdx.x;
    int l = 0, ticket = 0;
    bool act = i < nw;
    if (act) {
        l = lengths[i];
        ticket = atomicAdd(&lcnt[l], 1);
    }
    __syncthreads();
    if (threadIdx.x < 25 && lcnt[threadIdx.x] > 0)
        lbase[threadIdx.x] = atomicAdd(&ws[50 + threadIdx.x], lcnt[threadIdx.x]);
    __syncthreads();
    if (act) ws[100 + ws[25 + l] + lbase[l] + ticket] = i;
}

// ---------------- fused packing kernel ----------------
// Part 1: xtab[dir][v][m][s][q] bf16 = prescale*(b[row] + Wih[row]·emb[v]),
//   row = q*HID + j, j = off(s)+m (0 for pad rows).
// Part 2: h-part weight fragments wp[dir][m][kcp][lane][8], k=(kcp+2)*32+8*grp+i.
__global__ void pack_all_kernel(const float* __restrict__ emb,
                                const float* __restrict__ Wih_f, const float* __restrict__ Whh_f,
                                const float* __restrict__ b_f,
                                const float* __restrict__ Wih_b, const float* __restrict__ Whh_b,
                                const float* __restrict__ b_b,
                                unsigned short* __restrict__ xtab,
                                unsigned short* __restrict__ wp, int vocab) {
    int tid0 = blockIdx.x * blockDim.x + threadIdx.x;
    int xtTotal = 2 * vocab * NT * 16;
    if (tid0 < xtTotal) {
        int q = tid0 & 3, s = (tid0 >> 2) & 3;
        int m = (tid0 >> 4) % NT;
        int vv = (tid0 >> 4) / NT;          // dir*vocab + v
        int v = vv % vocab, dir = vv / vocab;
        int cnt_s = (s < 2) ? 13 : 12;
        float val = 0.0f;
        if (m < cnt_s) {
            int j = 13 * s - (s == 3 ? 1 : 0) + m;
            int row = q * HID + j;
            const float* W  = dir ? Wih_b : Wih_f;
            const float* bv = dir ? b_b   : b_f;
            float acc = bv[row];
            const float* wr = W + row * EMBD;
            const float* ev = emb + v * EMBD;
            for (int e = 0; e < EMBD; ++e) acc += wr[e] * ev[e];
            val = acc * ((q == 2) ? (2.0f * LOG2E) : LOG2E);
        }
        xtab[tid0] = f2bf(val);
        return;
    }
    int tid = tid0 - xtTotal;
    if (tid >= 2 * NT * 1024) return;
    int i    = tid & 7;
    int lane = (tid >> 3) & 63;
    int kcp  = (tid >> 9) & 1;
    int rem  = tid >> 10;
    int m    = rem % NT;
    int dir  = rem / NT;
    const float* Whh = dir ? Whh_b : Whh_f;

    int p = lane & 15, grp = lane >> 4;
    int k = (kcp + 2) * 32 + 8 * grp + i;
    int s = p >> 2, q = p & 3;
    int cnt_s = (s < 2) ? 13 : 12;
    float val = 0.0f;
    if (m < cnt_s) {
        int j = 13 * s - (s == 3 ? 1 : 0) + m;
        int row = q * HID + j;
        int kk = k - 64;
        int half = kk >> 5;
        int s2 = (kk >> 3) & 3;
        int r = kk & 7;
        int mcol = half * 8 + r;
        int cnt2 = (s2 < 2) ? 13 : 12;
        if (mcol < cnt2) {
            int jc = 13 * s2 - (s2 == 3 ? 1 : 0) + mcol;
            val = Whh[row * HID + jc] * ((q == 2) ? (2.0f * LOG2E) : LOG2E);
        }
    }
    wp[tid] = f2bf(val);
}

// ---------------- main MFMA kernel: h-part MFMA + x-part table ----------------
#define MFMA16(AW, BB, ACC) __builtin_amdgcn_mfma_f32_16x16x32_bf16((AW), (BB), (ACC), 0, 0, 0)

#define TTMH(M, XT, C, H) {                                        \
    const short8 w2 = *(const short8*)(sWl + ((M)*2+0)*512);       \
    const short8 w3 = *(const short8*)(sWl + ((M)*2+1)*512);       \
    f32x4 ah = zz;                                                 \
    ah = MFMA16(w2, bh0, ah);                                      \
    ah = MFMA16(w3, bh1, ah);                                      \
    float ai = ah[0] + __uint_as_float((XT).x << 16);              \
    float af = ah[1] + __uint_as_float((XT).x & 0xffff0000u);      \
    float ag = ah[2] + __uint_as_float((XT).y << 16);              \
    float ao = ah[3] + __uint_as_float((XT).y & 0xffff0000u);      \
    float cn = s2f(af) * (C) + s2f(ai) * t2f(ag);                  \
    float hn = s2f(ao) * tanhrt(cn);                               \
    (C) = upd ? cn : (C);                                          \
    (H) = upd ? hn : (H); }

__global__ __launch_bounds__(BLK, 2)
void bilstm_mfma_kernel(const int* __restrict__ chars,
                        const int* __restrict__ lengths,
                        const int* __restrict__ perm,
                        const unsigned short* __restrict__ xtab,
                        const unsigned short* __restrict__ wp,
                        float* __restrict__ out, int nw, int ml, int vocab)
{
    const int dir = blockIdx.y;
    __shared__ unsigned short sW[NT * 2 * 512];   // 26 KB h-part fragments
    {
        const float4* src = (const float4*)(wp + dir * (NT * 2 * 512));
        float4* dst = (float4*)sW;
        for (int i = threadIdx.x; i < NT * 2 * 512 / 8; i += BLK) dst[i] = src[i];
    }
    __syncthreads();

    const int lane = threadIdx.x & 63;
    const int wv   = threadIdx.x >> 6;
    const int wcol = lane & 15;
    const int s    = lane >> 4;

    int gidx = (blockIdx.x * 4 + wv) * 16 + wcol;
    gidx = imin(gidx, nw - 1);
    const int word = perm[gidx];
    const int len  = lengths[word];

    int lmax = len;
    lmax = imax(lmax, __shfl_xor(lmax, 1));
    lmax = imax(lmax, __shfl_xor(lmax, 2));
    lmax = imax(lmax, __shfl_xor(lmax, 4));
    lmax = imax(lmax, __shfl_xor(lmax, 8));

    const int* charp = chars + (size_t)word * ml;
    const unsigned short* sWl = sW + lane * 8;
    // per-(dir,lane) table base; per-ch stride = NT*16 u16
    const unsigned short* xdir = xtab + (size_t)dir * vocab * (NT * 16) + s * 4;

    const f32x4 zz = {0.0f, 0.0f, 0.0f, 0.0f};
    float c00=0,c01=0,c02=0,c03=0,c04=0,c05=0,c06=0,c07=0,c08=0,c09=0,c10=0,c11=0,c12=0;
    float h00=0,h01=0,h02=0,h03=0,h04=0,h05=0,h06=0,h07=0,h08=0,h09=0,h10=0,h11=0,h12=0;
    short8 bh0, bh1;
#pragma unroll
    for (int i2 = 0; i2 < 8; ++i2) { bh0[i2] = 0; bh1[i2] = 0; }

    int chcur = 0;
    if (lmax > 0) {
        int pos0 = dir ? imax(len - 1, 0) : 0;
        chcur = charp[pos0];
    }

    for (int t = 0; t < lmax; ++t) {
        const unsigned short* xb = xdir + (size_t)chcur * (NT * 16);
        uint2 xt0  = *(const uint2*)(xb + 0*16);
        uint2 xt1  = *(const uint2*)(xb + 1*16);
        uint2 xt2  = *(const uint2*)(xb + 2*16);
        uint2 xt3  = *(const uint2*)(xb + 3*16);
        uint2 xt4  = *(const uint2*)(xb + 4*16);
        uint2 xt5  = *(const uint2*)(xb + 5*16);
        uint2 xt6  = *(const uint2*)(xb + 6*16);
        uint2 xt7  = *(const uint2*)(xb + 7*16);
        uint2 xt8  = *(const uint2*)(xb + 8*16);
        uint2 xt9  = *(const uint2*)(xb + 9*16);
        uint2 xt10 = *(const uint2*)(xb + 10*16);
        uint2 xt11 = *(const uint2*)(xb + 11*16);
        uint2 xt12 = *(const uint2*)(xb + 12*16);

        int tn = (t + 1 < lmax) ? t + 1 : t;
        int posn = dir ? imax(len - 1 - tn, 0) : tn;
        int chnext = charp[posn];

        const bool upd = (t < len);
        TTMH(0,  xt0,  c00, h00)
        TTMH(1,  xt1,  c01, h01)
        TTMH(2,  xt2,  c02, h02)
        TTMH(3,  xt3,  c03, h03)
        TTMH(4,  xt4,  c04, h04)
        TTMH(5,  xt5,  c05, h05)
        TTMH(6,  xt6,  c06, h06)
        TTMH(7,  xt7,  c07, h07)
        TTMH(8,  xt8,  c08, h08)
        TTMH(9,  xt9,  c09, h09)
        TTMH(10, xt10, c10, h10)
        TTMH(11, xt11, c11, h11)
        TTMH(12, xt12, c12, h12)

        u32x4 p0, p1;
        p0[0] = cvtpk(h00, h01); p0[1] = cvtpk(h02, h03);
        p0[2] = cvtpk(h04, h05); p0[3] = cvtpk(h06, h07);
        p1[0] = cvtpk(h08, h09); p1[1] = cvtpk(h10, h11);
        p1[2] = cvtpk(h12, 0.0f); p1[3] = 0u;
        bh0 = __builtin_bit_cast(short8, p0);
        bh1 = __builtin_bit_cast(short8, p1);

        chcur = chnext;
    }

    int offs = 13 * s - (s == 3 ? 1 : 0);
    float* outw = out + (size_t)word * (2 * HID) + dir * HID + offs;
    outw[0] = h00; outw[1] = h01; outw[2]  = h02; outw[3]  = h03;
    outw[4] = h04; outw[5] = h05; outw[6]  = h06; outw[7]  = h07;
    outw[8] = h08; outw[9] = h09; outw[10] = h10; outw[11] = h11;
    if (s < 2) outw[12] = h12;
}

// ---------------- R1 fallback (scalar f32) ----------------
__global__ __launch_bounds__(BLK, 2)
void bilstm_fallback_kernel(const int* __restrict__ chars,
                            const int* __restrict__ lengths,
                            const float* __restrict__ emb,
                            const float* __restrict__ Wih_f, const float* __restrict__ Whh_f, const float* __restrict__ b_f,
                            const float* __restrict__ Wih_b, const float* __restrict__ Whh_b, const float* __restrict__ b_b,
                            const int* __restrict__ perm,
                            float* __restrict__ out, int nw, int ml)
{
    const int dir = blockIdx.y;
    const float* Wih = dir ? Wih_b : Wih_f;
    const float* Whh = dir ? Whh_b : Whh_f;
    const float* bv  = dir ? b_b  : b_f;
    __shared__ float4 sWU4[HID * 100];
    __shared__ float4 sB4[HID];
    {
        float* p = (float*)sWU4;
        for (int i = threadIdx.x; i < HID * 100 * 4; i += BLK) {
            int g = i & 3, r = i >> 2, j = r / 100, k = r - j * 100;
            p[i] = (k < EMBD) ? Wih[(j + g * HID) * EMBD + k]
                              : Whh[(j + g * HID) * HID + (k - EMBD)];
        }
        if (threadIdx.x < HID) {
            int j = threadIdx.x;
            sB4[j] = make_float4(bv[j], bv[j + HID], bv[j + 2*HID], bv[j + 3*HID]);
        }
    }
    __syncthreads();
    int gid = blockIdx.x * BLK + threadIdx.x;
    if (gid >= nw) return;
    int word = perm ? perm[gid] : gid;
    int len  = lengths[word];
    float h[HID], x[EMBD], c[HID], hn[HID];
#pragma unroll
    for (int j = 0; j < HID; ++j) h[j] = 0.f;
#pragma unroll 1
    for (int j = 0; j < HID; ++j) c[j] = 0.f;
    const int* wch = chars + word * ml;
    float* op = out + (size_t)word * (2 * HID) + dir * HID;
#pragma unroll 1
    for (int t = 0; t < len; ++t) {
        int pos = dir ? (len - 1 - t) : t;
        int ch = wch[pos];
        const float2* ep = (const float2*)(emb + ch * EMBD);
#pragma unroll
        for (int k = 0; k < EMBD / 2; ++k) { float2 v = ep[k]; x[2*k] = v.x; x[2*k+1] = v.y; }
#pragma unroll 1
        for (int j = 0; j < HID; ++j) {
            const float4* wpt = sWU4 + j * 100;
            float4 bb = sB4[j];
            float gi = bb.x, gf = bb.y, gg = bb.z, go = bb.w;
#pragma unroll
            for (int k = 0; k < EMBD; ++k) {
                float4 w = wpt[k]; float xv = x[k];
                gi += w.x*xv; gf += w.y*xv; gg += w.z*xv; go += w.w*xv;
            }
#pragma unroll
            for (int k = 0; k < HID; ++k) {
                float4 w = wpt[EMBD + k]; float hv = h[k];
                gi += w.x*hv; gf += w.y*hv; gg += w.z*hv; go += w.w*hv;
            }
            float cn = sigm(gf) * c[j] + sigm(gi) * tanhfast(gg);
            c[j] = cn;
            hn[j] = sigm(go) * tanhfast(cn);
        }
#pragma unroll
        for (int j = 0; j < HID; ++j) h[j] = hn[j];
    }
#pragma unroll
    for (int j = 0; j < HID / 2; ++j)
        ((float2*)op)[j] = make_float2(h[2*j], h[2*j+1]);
}

extern "C" void kernel_launch(void* const* d_in, const int* in_sizes, int n_in,
                              void* d_out, int out_size, void* d_ws, size_t ws_size,
                              hipStream_t stream) {
    const int*   chars = (const int*)  d_in[0];
    const int*   lens  = (const int*)  d_in[1];
    const float* emb   = (const float*)d_in[2];
    const float* Wih_f = (const float*)d_in[3];
    const float* Whh_f = (const float*)d_in[4];
    const float* b_f   = (const float*)d_in[5];
    const float* Wih_b = (const float*)d_in[6];
    const float* Whh_b = (const float*)d_in[7];
    const float* b_b   = (const float*)d_in[8];
    float* out = (float*)d_out;

    const int nw    = in_sizes[1];
    const int ml    = in_sizes[0] / nw;
    const int vocab = in_sizes[2] / EMBD;

    size_t sortNeed = (size_t)(100 + nw) * 4;
    size_t xtOff    = (sortNeed + 255) & ~(size_t)255;
    size_t xtBytes  = (size_t)2 * vocab * NT * 16 * 2;
    size_t wOff     = (xtOff + xtBytes + 1023) & ~(size_t)1023;
    size_t wBytes   = (size_t)2 * NT * 1024 * 2;
    size_t need     = wOff + wBytes;

    int* ws = (int*)d_ws;
    bool haveSort = ws_size >= sortNeed;
    if (haveSort) {
        zero_counts_kernel<<<1, 128, 0, stream>>>(ws);
        hist_kernel<<<(nw + 255) / 256, 256, 0, stream>>>(lens, ws, nw);
        prefix_kernel<<<1, 1, 0, stream>>>(ws);
        scatter_kernel<<<(nw + 255) / 256, 256, 0, stream>>>(lens, ws, nw);
    }

    if (ws_size >= need && haveSort) {
        unsigned short* xtab = (unsigned short*)((char*)d_ws + xtOff);
        unsigned short* wpk  = (unsigned short*)((char*)d_ws + wOff);
        int packTot = 2 * vocab * NT * 16 + 2 * NT * 1024;
        pack_all_kernel<<<(packTot + 255) / 256, 256, 0, stream>>>(
            emb, Wih_f, Whh_f, b_f, Wih_b, Whh_b, b_b, xtab, wpk, vocab);
        dim3 grid((nw + 63) / 64, 2);
        bilstm_mfma_kernel<<<grid, BLK, 0, stream>>>(chars, lens, ws + 100, xtab, wpk,
                                                     out, nw, ml, vocab);
    } else {
        dim3 grid((nw + BLK - 1) / BLK, 2);
        bilstm_fallback_kernel<<<grid, BLK, 0, stream>>>(chars, lens, emb,
                                                         Wih_f, Whh_f, b_f,
                                                         Wih_b, Whh_b, b_b,
                                                         haveSort ? ws + 100 : nullptr,
                                                         out, nw, ml);
    }
}

// Round 19
// 218.010 us; speedup vs baseline: 5.8836x; 1.1046x over previous
//
#include <hip/hip_runtime.h>

#define EMBD 50
#define HID 50
#define BLK 256
#define NT 13               // gate tiles: 13*16 = 208 rows >= 200 real gates
#define LOG2E 1.44269504f

typedef float f32x4 __attribute__((ext_vector_type(4)));
typedef short short8 __attribute__((ext_vector_type(8)));
typedef unsigned u32x4 __attribute__((ext_vector_type(4)));

__device__ __forceinline__ int imax(int a, int b) { return a > b ? a : b; }
__device__ __forceinline__ int imin(int a, int b) { return a < b ? a : b; }

__device__ __forceinline__ unsigned short f2bf(float f) {
    unsigned u = __float_as_uint(f);
    u += 0x7FFFu + ((u >> 16) & 1u);
    return (unsigned short)(u >> 16);
}
__device__ __forceinline__ unsigned cvtpk(float a, float b) {
    unsigned r;
    asm("v_cvt_pk_bf16_f32 %0, %1, %2" : "=v"(r) : "v"(a), "v"(b));
    return r;
}
// (fallback only)
__device__ __forceinline__ float sigm(float x) {
    return __fdividef(1.0f, 1.0f + __expf(-x));
}
__device__ __forceinline__ float tanhfast(float x) {
    float e = __expf(2.0f * x);
    return 1.0f - __fdividef(2.0f, e + 1.0f);
}

// ---------------- length bucket sort ----------------
__global__ void zero_counts_kernel(int* ws) {
    if (threadIdx.x < 75) ws[threadIdx.x] = 0;
}
__global__ void hist_kernel(const int* __restrict__ lengths, int* ws, int nw) {
    __shared__ int lc[32];
    if (threadIdx.x < 32) lc[threadIdx.x] = 0;
    __syncthreads();
    int i = blockIdx.x * blockDim.x + threadIdx.x;
    if (i < nw) atomicAdd(&lc[lengths[i]], 1);
    __syncthreads();
    if (threadIdx.x < 25 && lc[threadIdx.x] > 0)
        atomicAdd(&ws[threadIdx.x], lc[threadIdx.x]);
}
__global__ void prefix_kernel(int* ws) {
    if (threadIdx.x == 0 && blockIdx.x == 0) {
        int acc = 0;
        for (int l = 0; l <= 24; ++l) { ws[25 + l] = acc; acc += ws[l]; }
    }
}
__global__ void scatter_kernel(const int* __restrict__ lengths, int* ws, int nw) {
    __shared__ int lcnt[32], lbase[32];
    if (threadIdx.x < 32) lcnt[threadIdx.x] = 0;
    __syncthreads();
    int i = blockIdx.x * blockDim.x + threadIdx.x;
    int l = 0, ticket = 0;
    bool act = i < nw;
    if (act) {
        l = lengths[i];
        ticket = atomicAdd(&lcnt[l], 1);
    }
    __syncthreads();
    if (threadIdx.x < 25 && lcnt[threadIdx.x] > 0)
        lbase[threadIdx.x] = atomicAdd(&ws[50 + threadIdx.x], lcnt[threadIdx.x]);
    __syncthreads();
    if (act) ws[100 + ws[25 + l] + lbase[l] + ticket] = i;
}

// ---------------- fused packing kernel ----------------
// Part 1: xtab[dir][v][m][s][q] bf16 = prescale*(b[row] + Wih[row]·emb[v]),
//   row = q*HID + j, j = off(s)+m (0 for pad rows).
// Part 2: h-part weight fragments wp[dir][m][kcp][lane][8], k=(kcp+2)*32+8*grp+i.
// Prescale: i,f,o rows by log2e; g rows by 2*log2e.
__global__ void pack_all_kernel(const float* __restrict__ emb,
                                const float* __restrict__ Wih_f, const float* __restrict__ Whh_f,
                                const float* __restrict__ b_f,
                                const float* __restrict__ Wih_b, const float* __restrict__ Whh_b,
                                const float* __restrict__ b_b,
                                unsigned short* __restrict__ xtab,
                                unsigned short* __restrict__ wp, int vocab) {
    int tid0 = blockIdx.x * blockDim.x + threadIdx.x;
    int xtTotal = 2 * vocab * NT * 16;
    if (tid0 < xtTotal) {
        int q = tid0 & 3, s = (tid0 >> 2) & 3;
        int m = (tid0 >> 4) % NT;
        int vv = (tid0 >> 4) / NT;          // dir*vocab + v
        int v = vv % vocab, dir = vv / vocab;
        int cnt_s = (s < 2) ? 13 : 12;
        float val = 0.0f;
        if (m < cnt_s) {
            int j = 13 * s - (s == 3 ? 1 : 0) + m;
            int row = q * HID + j;
            const float* W  = dir ? Wih_b : Wih_f;
            const float* bv = dir ? b_b   : b_f;
            float acc = bv[row];
            const float* wr = W + row * EMBD;
            const float* ev = emb + v * EMBD;
            for (int e = 0; e < EMBD; ++e) acc += wr[e] * ev[e];
            val = acc * ((q == 2) ? (2.0f * LOG2E) : LOG2E);
        }
        xtab[tid0] = f2bf(val);
        return;
    }
    int tid = tid0 - xtTotal;
    if (tid >= 2 * NT * 1024) return;
    int i    = tid & 7;
    int lane = (tid >> 3) & 63;
    int kcp  = (tid >> 9) & 1;
    int rem  = tid >> 10;
    int m    = rem % NT;
    int dir  = rem / NT;
    const float* Whh = dir ? Whh_b : Whh_f;

    int p = lane & 15, grp = lane >> 4;
    int k = (kcp + 2) * 32 + 8 * grp + i;
    int s = p >> 2, q = p & 3;
    int cnt_s = (s < 2) ? 13 : 12;
    float val = 0.0f;
    if (m < cnt_s) {
        int j = 13 * s - (s == 3 ? 1 : 0) + m;
        int row = q * HID + j;
        int kk = k - 64;
        int half = kk >> 5;
        int s2 = (kk >> 3) & 3;
        int r = kk & 7;
        int mcol = half * 8 + r;
        int cnt2 = (s2 < 2) ? 13 : 12;
        if (mcol < cnt2) {
            int jc = 13 * s2 - (s2 == 3 ? 1 : 0) + mcol;
            val = Whh[row * HID + jc] * ((q == 2) ? (2.0f * LOG2E) : LOG2E);
        }
    }
    wp[tid] = f2bf(val);
}

// ---------------- main MFMA kernel: h-part MFMA + x-part table ----------------
#define MFMA16(AW, BB, ACC) __builtin_amdgcn_mfma_f32_16x16x32_bf16((AW), (BB), (ACC), 0, 0, 0)

// Single-rcp gate update. Inputs prescaled (i,f,o: log2e; g: 2log2e):
//   cn = [c(1+ei)(eg+1) + (1+ef)(eg-1)] / [(1+ef)(1+ei)(eg+1)]
//   hn = (ec-1) / [(1+eo)(ec+1)],  ec = 2^(2log2e*cn)
// 5 exp2 + 2 rcp per element (was 5+5). Pad elements (all-zero gates) give
// cn = c/2 -> harmless (outputs unused, feedback columns zeroed).
#define TTMH(M, XT, C, H) {                                        \
    const short8 w2 = *(const short8*)(sWl + ((M)*2+0)*512);       \
    const short8 w3 = *(const short8*)(sWl + ((M)*2+1)*512);       \
    f32x4 ah = zz;                                                 \
    ah = MFMA16(w2, bh0, ah);                                      \
    ah = MFMA16(w3, bh1, ah);                                      \
    float ai = ah[0] + __uint_as_float((XT).x << 16);              \
    float af = ah[1] + __uint_as_float((XT).x & 0xffff0000u);      \
    float ag = ah[2] + __uint_as_float((XT).y << 16);              \
    float ao = ah[3] + __uint_as_float((XT).y & 0xffff0000u);      \
    float ei = __builtin_amdgcn_exp2f(-ai);                        \
    float ef = __builtin_amdgcn_exp2f(-af);                        \
    float eg = __builtin_amdgcn_exp2f(ag);                         \
    float eo = __builtin_amdgcn_exp2f(-ao);                        \
    float a1 = 1.0f + ef, a2 = 1.0f + ei;                          \
    float a3 = eg + 1.0f, a4 = eg - 1.0f;                          \
    float p1 = a2 * a3;                                            \
    float nn = fmaf(a1, a4, (C) * p1);                             \
    float dd = a1 * p1;                                            \
    float cn = nn * __builtin_amdgcn_rcpf(dd);                     \
    float ec = __builtin_amdgcn_exp2f((2.0f * LOG2E) * cn);        \
    float b2 = ec + 1.0f, b3 = ec - 1.0f;                          \
    float qd = (1.0f + eo) * b2;                                   \
    float hn = b3 * __builtin_amdgcn_rcpf(qd);                     \
    (C) = upd ? cn : (C);                                          \
    (H) = upd ? hn : (H); }

__global__ __launch_bounds__(BLK, 2)
void bilstm_mfma_kernel(const int* __restrict__ chars,
                        const int* __restrict__ lengths,
                        const int* __restrict__ perm,
                        const unsigned short* __restrict__ xtab,
                        const unsigned short* __restrict__ wp,
                        float* __restrict__ out, int nw, int ml, int vocab)
{
    const int dir = blockIdx.y;
    __shared__ unsigned short sW[NT * 2 * 512];   // 26 KB h-part fragments
    {
        const float4* src = (const float4*)(wp + dir * (NT * 2 * 512));
        float4* dst = (float4*)sW;
        for (int i = threadIdx.x; i < NT * 2 * 512 / 8; i += BLK) dst[i] = src[i];
    }
    __syncthreads();

    const int lane = threadIdx.x & 63;
    const int wv   = threadIdx.x >> 6;
    const int wcol = lane & 15;
    const int s    = lane >> 4;

    int gidx = (blockIdx.x * 4 + wv) * 16 + wcol;
    gidx = imin(gidx, nw - 1);
    gidx = nw - 1 - gidx;        // LPT: longest words in block 0 (launch first)
    const int word = perm[gidx];
    const int len  = lengths[word];

    int lmax = len;
    lmax = imax(lmax, __shfl_xor(lmax, 1));
    lmax = imax(lmax, __shfl_xor(lmax, 2));
    lmax = imax(lmax, __shfl_xor(lmax, 4));
    lmax = imax(lmax, __shfl_xor(lmax, 8));

    const int* charp = chars + (size_t)word * ml;
    const unsigned short* sWl = sW + lane * 8;
    const unsigned short* xdir = xtab + (size_t)dir * vocab * (NT * 16) + s * 4;

    const f32x4 zz = {0.0f, 0.0f, 0.0f, 0.0f};
    float c00=0,c01=0,c02=0,c03=0,c04=0,c05=0,c06=0,c07=0,c08=0,c09=0,c10=0,c11=0,c12=0;
    float h00=0,h01=0,h02=0,h03=0,h04=0,h05=0,h06=0,h07=0,h08=0,h09=0,h10=0,h11=0,h12=0;
    short8 bh0, bh1;
#pragma unroll
    for (int i2 = 0; i2 < 8; ++i2) { bh0[i2] = 0; bh1[i2] = 0; }

    int chcur = 0;
    if (lmax > 0) {
        int pos0 = dir ? imax(len - 1, 0) : 0;
        chcur = charp[pos0];
    }

    for (int t = 0; t < lmax; ++t) {
        const unsigned short* xb = xdir + (size_t)chcur * (NT * 16);
        uint2 xt0  = *(const uint2*)(xb + 0*16);
        uint2 xt1  = *(const uint2*)(xb + 1*16);
        uint2 xt2  = *(const uint2*)(xb + 2*16);
        uint2 xt3  = *(const uint2*)(xb + 3*16);
        uint2 xt4  = *(const uint2*)(xb + 4*16);
        uint2 xt5  = *(const uint2*)(xb + 5*16);
        uint2 xt6  = *(const uint2*)(xb + 6*16);
        uint2 xt7  = *(const uint2*)(xb + 7*16);
        uint2 xt8  = *(const uint2*)(xb + 8*16);
        uint2 xt9  = *(const uint2*)(xb + 9*16);
        uint2 xt10 = *(const uint2*)(xb + 10*16);
        uint2 xt11 = *(const uint2*)(xb + 11*16);
        uint2 xt12 = *(const uint2*)(xb + 12*16);

        int tn = (t + 1 < lmax) ? t + 1 : t;
        int posn = dir ? imax(len - 1 - tn, 0) : tn;
        int chnext = charp[posn];

        const bool upd = (t < len);
        TTMH(0,  xt0,  c00, h00)
        TTMH(1,  xt1,  c01, h01)
        TTMH(2,  xt2,  c02, h02)
        TTMH(3,  xt3,  c03, h03)
        TTMH(4,  xt4,  c04, h04)
        TTMH(5,  xt5,  c05, h05)
        TTMH(6,  xt6,  c06, h06)
        TTMH(7,  xt7,  c07, h07)
        TTMH(8,  xt8,  c08, h08)
        TTMH(9,  xt9,  c09, h09)
        TTMH(10, xt10, c10, h10)
        TTMH(11, xt11, c11, h11)
        TTMH(12, xt12, c12, h12)

        u32x4 p0, p1;
        p0[0] = cvtpk(h00, h01); p0[1] = cvtpk(h02, h03);
        p0[2] = cvtpk(h04, h05); p0[3] = cvtpk(h06, h07);
        p1[0] = cvtpk(h08, h09); p1[1] = cvtpk(h10, h11);
        p1[2] = cvtpk(h12, 0.0f); p1[3] = 0u;
        bh0 = __builtin_bit_cast(short8, p0);
        bh1 = __builtin_bit_cast(short8, p1);

        chcur = chnext;
    }

    int offs = 13 * s - (s == 3 ? 1 : 0);
    float* outw = out + (size_t)word * (2 * HID) + dir * HID + offs;
    outw[0] = h00; outw[1] = h01; outw[2]  = h02; outw[3]  = h03;
    outw[4] = h04; outw[5] = h05; outw[6]  = h06; outw[7]  = h07;
    outw[8] = h08; outw[9] = h09; outw[10] = h10; outw[11] = h11;
    if (s < 2) outw[12] = h12;
}

// ---------------- R1 fallback (scalar f32) ----------------
__global__ __launch_bounds__(BLK, 2)
void bilstm_fallback_kernel(const int* __restrict__ chars,
                            const int* __restrict__ lengths,
                            const float* __restrict__ emb,
                            const float* __restrict__ Wih_f, const float* __restrict__ Whh_f, const float* __restrict__ b_f,
                            const float* __restrict__ Wih_b, const float* __restrict__ Whh_b, const float* __restrict__ b_b,
                            const int* __restrict__ perm,
                            float* __restrict__ out, int nw, int ml)
{
    const int dir = blockIdx.y;
    const float* Wih = dir ? Wih_b : Wih_f;
    const float* Whh = dir ? Whh_b : Whh_f;
    const float* bv  = dir ? b_b  : b_f;
    __shared__ float4 sWU4[HID * 100];
    __shared__ float4 sB4[HID];
    {
        float* p = (float*)sWU4;
        for (int i = threadIdx.x; i < HID * 100 * 4; i += BLK) {
            int g = i & 3, r = i >> 2, j = r / 100, k = r - j * 100;
            p[i] = (k < EMBD) ? Wih[(j + g * HID) * EMBD + k]
                              : Whh[(j + g * HID) * HID + (k - EMBD)];
        }
        if (threadIdx.x < HID) {
            int j = threadIdx.x;
            sB4[j] = make_float4(bv[j], bv[j + HID], bv[j + 2*HID], bv[j + 3*HID]);
        }
    }
    __syncthreads();
    int gid = blockIdx.x * BLK + threadIdx.x;
    if (gid >= nw) return;
    int word = perm ? perm[gid] : gid;
    int len  = lengths[word];
    float h[HID], x[EMBD], c[HID], hn[HID];
#pragma unroll
    for (int j = 0; j < HID; ++j) h[j] = 0.f;
#pragma unroll 1
    for (int j = 0; j < HID; ++j) c[j] = 0.f;
    const int* wch = chars + word * ml;
    float* op = out + (size_t)word * (2 * HID) + dir * HID;
#pragma unroll 1
    for (int t = 0; t < len; ++t) {
        int pos = dir ? (len - 1 - t) : t;
        int ch = wch[pos];
        const float2* ep = (const float2*)(emb + ch * EMBD);
#pragma unroll
        for (int k = 0; k < EMBD / 2; ++k) { float2 v = ep[k]; x[2*k] = v.x; x[2*k+1] = v.y; }
#pragma unroll 1
        for (int j = 0; j < HID; ++j) {
            const float4* wpt = sWU4 + j * 100;
            float4 bb = sB4[j];
            float gi = bb.x, gf = bb.y, gg = bb.z, go = bb.w;
#pragma unroll
            for (int k = 0; k < EMBD; ++k) {
                float4 w = wpt[k]; float xv = x[k];
                gi += w.x*xv; gf += w.y*xv; gg += w.z*xv; go += w.w*xv;
            }
#pragma unroll
            for (int k = 0; k < HID; ++k) {
                float4 w = wpt[EMBD + k]; float hv = h[k];
                gi += w.x*hv; gf += w.y*hv; gg += w.z*hv; go += w.w*hv;
            }
            float cn = sigm(gf) * c[j] + sigm(gi) * tanhfast(gg);
            c[j] = cn;
            hn[j] = sigm(go) * tanhfast(cn);
        }
#pragma unroll
        for (int j = 0; j < HID; ++j) h[j] = hn[j];
    }
#pragma unroll
    for (int j = 0; j < HID / 2; ++j)
        ((float2*)op)[j] = make_float2(h[2*j], h[2*j+1]);
}

extern "C" void kernel_launch(void* const* d_in, const int* in_sizes, int n_in,
                              void* d_out, int out_size, void* d_ws, size_t ws_size,
                              hipStream_t stream) {
    const int*   chars = (const int*)  d_in[0];
    const int*   lens  = (const int*)  d_in[1];
    const float* emb   = (const float*)d_in[2];
    const float* Wih_f = (const float*)d_in[3];
    const float* Whh_f = (const float*)d_in[4];
    const float* b_f   = (const float*)d_in[5];
    const float* Wih_b = (const float*)d_in[6];
    const float* Whh_b = (const float*)d_in[7];
    const float* b_b   = (const float*)d_in[8];
    float* out = (float*)d_out;

    const int nw    = in_sizes[1];
    const int ml    = in_sizes[0] / nw;
    const int vocab = in_sizes[2] / EMBD;

    size_t sortNeed = (size_t)(100 + nw) * 4;
    size_t xtOff    = (sortNeed + 255) & ~(size_t)255;
    size_t xtBytes  = (size_t)2 * vocab * NT * 16 * 2;
    size_t wOff     = (xtOff + xtBytes + 1023) & ~(size_t)1023;
    size_t wBytes   = (size_t)2 * NT * 1024 * 2;
    size_t need     = wOff + wBytes;

    int* ws = (int*)d_ws;
    bool haveSort = ws_size >= sortNeed;
    if (haveSort) {
        zero_counts_kernel<<<1, 128, 0, stream>>>(ws);
        hist_kernel<<<(nw + 255) / 256, 256, 0, stream>>>(lens, ws, nw);
        prefix_kernel<<<1, 1, 0, stream>>>(ws);
        scatter_kernel<<<(nw + 255) / 256, 256, 0, stream>>>(lens, ws, nw);
    }

    if (ws_size >= need && haveSort) {
        unsigned short* xtab = (unsigned short*)((char*)d_ws + xtOff);
        unsigned short* wpk  = (unsigned short*)((char*)d_ws + wOff);
        int packTot = 2 * vocab * NT * 16 + 2 * NT * 1024;
        pack_all_kernel<<<(packTot + 255) / 256, 256, 0, stream>>>(
            emb, Wih_f, Whh_f, b_f, Wih_b, Whh_b, b_b, xtab, wpk, vocab);
        dim3 grid((nw + 63) / 64, 2);
        bilstm_mfma_kernel<<<grid, BLK, 0, stream>>>(chars, lens, ws + 100, xtab, wpk,
                                                     out, nw, ml, vocab);
    } else {
        dim3 grid((nw + BLK - 1) / BLK, 2);
        bilstm_fallback_kernel<<<grid, BLK, 0, stream>>>(chars, lens, emb,
                                                         Wih_f, Whh_f, b_f,
                                                         Wih_b, Whh_b, b_b,
                                                         haveSort ? ws + 100 : nullptr,
                                                         out, nw, ml);
    }
}